// Round 1
// baseline (5447.441 us; speedup 1.0000x reference)
//
#include <hip/hip_runtime.h>
#include <float.h>

#define NN 50000
#define NE 800000
#define DF 96
#define DI 32
#define CO 128          // conv out
#define NG 500
#define HC 384          // hcat dim = 3*CO
#define F1I 384
#define F1O 160
#define F2O 10

// ---------------- degree ----------------
__global__ void k_deg(const int* __restrict__ dst, float* __restrict__ deg) {
    int e = blockIdx.x * blockDim.x + threadIdx.x;
    if (e < NE) atomicAdd(&deg[dst[e]], 1.0f);
}

// ---------------- graph boundaries (batch sorted) ----------------
__global__ void k_starts(const int* __restrict__ batch, int* __restrict__ start) {
    int i = blockIdx.x * blockDim.x + threadIdx.x;
    if (i >= NN) return;
    int b = batch[i];
    if (i == 0) {
        for (int g = 0; g <= b; ++g) start[g] = 0;
    } else {
        int p = batch[i - 1];
        if (p != b) for (int g = p + 1; g <= b; ++g) start[g] = i;
    }
    if (i == NN - 1) {
        for (int g = b + 1; g <= NG; ++g) start[g] = NN;
    }
}

// ---------------- build hin layer0: [x | info[batch]] din=128 ----------------
__global__ void k_hin0(const float* __restrict__ x, const float* __restrict__ info,
                       const int* __restrict__ batch, float* __restrict__ hin) {
    int tid = blockIdx.x * blockDim.x + threadIdx.x;  // NN*32 float4 slots
    if (tid >= NN * 32) return;
    int i = tid >> 5;
    int c = (tid & 31) * 4;
    float4 v;
    if (c < DF) v = *(const float4*)&x[i * DF + c];
    else        v = *(const float4*)&info[batch[i] * DI + (c - DF)];
    *(float4*)&hin[i * 128 + c] = v;
}

// ---------------- build hin layers1/2: [hcat[:,off:off+128] | info] din=160 ----------------
__global__ void k_hin(const float* __restrict__ hcat, int off, const float* __restrict__ info,
                      const int* __restrict__ batch, float* __restrict__ hin) {
    int tid = blockIdx.x * blockDim.x + threadIdx.x;  // NN*40 float4 slots
    if (tid >= NN * 40) return;
    int i = tid / 40;
    int c = (tid % 40) * 4;
    float4 v;
    if (c < CO) v = *(const float4*)&hcat[i * HC + off + c];
    else        v = *(const float4*)&info[batch[i] * DI + (c - CO)];
    *(float4*)&hin[i * 160 + c] = v;
}

// ---------------- edge scatter: agg[dst] += hin[src] ----------------
__global__ void k_scatter(const float* __restrict__ hin, const int* __restrict__ src,
                          const int* __restrict__ dst, float* __restrict__ agg, int din4) {
    int tid = blockIdx.x * blockDim.x + threadIdx.x;
    int total = NE * din4;
    if (tid >= total) return;
    int e = tid / din4;
    int c = (tid - e * din4) * 4;
    int din = din4 * 4;
    int s = src[e], d = dst[e];
    const float4 v = *(const float4*)&hin[s * din + c];
    float* ap = &agg[d * din + c];
    atomicAdd(ap + 0, v.x);
    atomicAdd(ap + 1, v.y);
    atomicAdd(ap + 2, v.z);
    atomicAdd(ap + 3, v.w);
}

// ---------------- dual GEMM: out = (agg/deg)@Wl + b + hin@Wr -> hcat[:, colOff..colOff+128) ----------------
#define BM 16
#define KC 32
__global__ __launch_bounds__(256) void k_gemm(const float* __restrict__ agg, const float* __restrict__ hin,
                                              const float* __restrict__ deg,
                                              const float* __restrict__ Wl, const float* __restrict__ Wr,
                                              const float* __restrict__ bias,
                                              float* __restrict__ hcat, int colOff, int din) {
    __shared__ float s_wl[KC][CO];
    __shared__ float s_wr[KC][CO];
    __shared__ float s_am[BM][KC + 1];
    __shared__ float s_ah[BM][KC + 1];
    __shared__ float s_rdeg[BM];

    int tid = threadIdx.x;
    int row = tid >> 4;        // 0..15
    int cg  = tid & 15;        // col group
    int j0  = cg * 8;
    int i0  = blockIdx.x * BM;

    if (tid < BM) {
        int i = i0 + tid;
        float dg = (i < NN) ? deg[i] : 1.0f;
        s_rdeg[tid] = 1.0f / fmaxf(dg, 1.0f);
    }

    float acc[8];
#pragma unroll
    for (int c = 0; c < 8; ++c) acc[c] = bias[j0 + c];

    int nChunks = din / KC;
    for (int kc = 0; kc < nChunks; ++kc) {
        int k0 = kc * KC;
        __syncthreads();
        // stage weight chunk: KC*128 floats each, as float4
        for (int t = tid; t < KC * CO / 4; t += 256) {
            int fi = t * 4;
            int k = fi >> 7;
            int j = fi & 127;
            *(float4*)&s_wl[k][j] = *(const float4*)&Wl[(k0 + k) * CO + j];
            *(float4*)&s_wr[k][j] = *(const float4*)&Wr[(k0 + k) * CO + j];
        }
        // stage A chunk (mean & hin)
        for (int t = tid; t < BM * KC; t += 256) {
            int r = t >> 5;
            int k = t & 31;
            int i = i0 + r;
            float av = 0.f, hv = 0.f;
            if (i < NN) {
                int gi = i * din + k0 + k;
                av = agg[gi];
                hv = hin[gi];
            }
            s_am[r][k] = av * s_rdeg[r];
            s_ah[r][k] = hv;
        }
        __syncthreads();
#pragma unroll
        for (int k = 0; k < KC; ++k) {
            float am = s_am[row][k];
            float ah = s_ah[row][k];
            float4 wl0 = *(float4*)&s_wl[k][j0];
            float4 wl1 = *(float4*)&s_wl[k][j0 + 4];
            float4 wr0 = *(float4*)&s_wr[k][j0];
            float4 wr1 = *(float4*)&s_wr[k][j0 + 4];
            acc[0] += am * wl0.x + ah * wr0.x;
            acc[1] += am * wl0.y + ah * wr0.y;
            acc[2] += am * wl0.z + ah * wr0.z;
            acc[3] += am * wl0.w + ah * wr0.w;
            acc[4] += am * wl1.x + ah * wr1.x;
            acc[5] += am * wl1.y + ah * wr1.y;
            acc[6] += am * wl1.z + ah * wr1.z;
            acc[7] += am * wl1.w + ah * wr1.w;
        }
    }
    int i = i0 + row;
    if (i < NN) {
        float4 o0 = make_float4(acc[0], acc[1], acc[2], acc[3]);
        float4 o1 = make_float4(acc[4], acc[5], acc[6], acc[7]);
        *(float4*)&hcat[i * HC + colOff + j0] = o0;
        *(float4*)&hcat[i * HC + colOff + j0 + 4] = o1;
    }
}

// ---------------- segment max pool over node ranges ----------------
__global__ void k_pool(const float* __restrict__ hcat, const int* __restrict__ start,
                       float* __restrict__ g) {
    int gr = blockIdx.x;
    int s = start[gr], e = start[gr + 1];
    for (int c = threadIdx.x; c < HC; c += blockDim.x) {
        float m = -FLT_MAX;
        for (int n = s; n < e; ++n) m = fmaxf(m, hcat[n * HC + c]);
        g[gr * HC + c] = m;
    }
}

// ---------------- FC head: out = relu(g@W1+b1)@W2+b2 ----------------
__global__ __launch_bounds__(192) void k_fc(const float* __restrict__ g,
                                            const float* __restrict__ W1, const float* __restrict__ b1,
                                            const float* __restrict__ W2, const float* __restrict__ b2,
                                            float* __restrict__ out) {
    __shared__ float s_g[F1I];
    __shared__ float s_z[F1O];
    int gr = blockIdx.x;
    int tid = threadIdx.x;
    for (int k = tid; k < F1I; k += 192) s_g[k] = g[gr * F1I + k];
    __syncthreads();
    if (tid < F1O) {
        float acc = b1[tid];
        for (int k = 0; k < F1I; ++k) acc += s_g[k] * W1[k * F1O + tid];
        s_z[tid] = fmaxf(acc, 0.0f);
    }
    __syncthreads();
    if (tid < F2O) {
        float a = b2[tid];
        for (int k = 0; k < F1O; ++k) a += s_z[k] * W2[k * F2O + tid];
        out[gr * F2O + tid] = a;
    }
}

extern "C" void kernel_launch(void* const* d_in, const int* in_sizes, int n_in,
                              void* d_out, int out_size, void* d_ws, size_t ws_size,
                              hipStream_t stream) {
    const float* x     = (const float*)d_in[0];
    const int*   eidx  = (const int*)d_in[1];
    const int*   batch = (const int*)d_in[2];
    const float* info  = (const float*)d_in[3];
    const float* Wl[3] = {(const float*)d_in[4], (const float*)d_in[7], (const float*)d_in[10]};
    const float* Wr[3] = {(const float*)d_in[5], (const float*)d_in[8], (const float*)d_in[11]};
    const float* bs[3] = {(const float*)d_in[6], (const float*)d_in[9], (const float*)d_in[12]};
    const float* Wfc1  = (const float*)d_in[13];
    const float* bfc1  = (const float*)d_in[14];
    const float* Wfc2  = (const float*)d_in[15];
    const float* bfc2  = (const float*)d_in[16];
    float* out = (float*)d_out;

    const int* src = eidx;
    const int* dst = eidx + NE;

    // workspace layout (floats)
    float* ws = (float*)d_ws;
    float* deg   = ws;                       // NN
    float* hin   = ws + 50000;               // NN*160
    float* agg   = ws + 8050000;             // NN*160
    float* hcat  = ws + 16050000;            // NN*384
    float* g     = ws + 35250000;            // NG*384
    int*   start = (int*)(ws + 35442000);    // NG+1

    // degree (once)
    hipMemsetAsync(deg, 0, NN * sizeof(float), stream);
    k_deg<<<(NE + 255) / 256, 256, 0, stream>>>(dst, deg);
    // graph boundaries (once)
    k_starts<<<(NN + 255) / 256, 256, 0, stream>>>(batch, start);

    // ---- layer 0 (din=128) ----
    k_hin0<<<(NN * 32 + 255) / 256, 256, 0, stream>>>(x, info, batch, hin);
    hipMemsetAsync(agg, 0, NN * 128 * sizeof(float), stream);
    k_scatter<<<(NE * 32 + 255) / 256, 256, 0, stream>>>(hin, src, dst, agg, 32);
    k_gemm<<<(NN + BM - 1) / BM, 256, 0, stream>>>(agg, hin, deg, Wl[0], Wr[0], bs[0], hcat, 0, 128);

    // ---- layer 1 (din=160) ----
    k_hin<<<(NN * 40 + 255) / 256, 256, 0, stream>>>(hcat, 0, info, batch, hin);
    hipMemsetAsync(agg, 0, NN * 160 * sizeof(float), stream);
    k_scatter<<<(NE * 40 + 255) / 256, 256, 0, stream>>>(hin, src, dst, agg, 40);
    k_gemm<<<(NN + BM - 1) / BM, 256, 0, stream>>>(agg, hin, deg, Wl[1], Wr[1], bs[1], hcat, 128, 160);

    // ---- layer 2 (din=160) ----
    k_hin<<<(NN * 40 + 255) / 256, 256, 0, stream>>>(hcat, 128, info, batch, hin);
    hipMemsetAsync(agg, 0, NN * 160 * sizeof(float), stream);
    k_scatter<<<(NE * 40 + 255) / 256, 256, 0, stream>>>(hin, src, dst, agg, 40);
    k_gemm<<<(NN + BM - 1) / BM, 256, 0, stream>>>(agg, hin, deg, Wl[2], Wr[2], bs[2], hcat, 256, 160);

    // ---- pool + head ----
    k_pool<<<NG, 128, 0, stream>>>(hcat, start, g);
    k_fc<<<NG, 192, 0, stream>>>(g, Wfc1, bfc1, Wfc2, bfc2, out);
}

// Round 2
// 1079.052 us; speedup vs baseline: 5.0484x; 5.0484x over previous
//
#include <hip/hip_runtime.h>
#include <float.h>

#define NN 50000
#define NE 800000
#define DF 96
#define DI 32
#define CO 128          // conv out
#define NG 500
#define HC 384          // hcat dim = 3*CO
#define F1I 384
#define F1O 160
#define F2O 10

// ---------------- CSR build: histogram of dst ----------------
__global__ void k_hist(const int* __restrict__ dst, int* __restrict__ cnt) {
    int e = blockIdx.x * blockDim.x + threadIdx.x;
    if (e < NE) atomicAdd(&cnt[dst[e]], 1);
}

// ---------------- single-block exclusive scan -> rowptr[NN+1] ----------------
__global__ __launch_bounds__(1024) void k_scan(const int* __restrict__ cnt, int* __restrict__ rowptr) {
    __shared__ int s[1024];
    int tid = threadIdx.x;
    const int per = (NN + 1023) / 1024;   // 49
    int base = tid * per;
    int local = 0;
    for (int k = 0; k < per; ++k) {
        int i = base + k;
        if (i < NN) local += cnt[i];
    }
    s[tid] = local;
    __syncthreads();
    for (int off = 1; off < 1024; off <<= 1) {
        int t = (tid >= off) ? s[tid - off] : 0;
        __syncthreads();
        s[tid] += t;
        __syncthreads();
    }
    int running = s[tid] - local;          // exclusive prefix
    for (int k = 0; k < per; ++k) {
        int i = base + k;
        if (i < NN) {
            rowptr[i] = running;
            running += cnt[i];
        }
    }
    if (tid == 1023) rowptr[NN] = s[1023];
}

// ---------------- bucket fill: csr[slot] = src ----------------
__global__ void k_fill(const int* __restrict__ src, const int* __restrict__ dst,
                       const int* __restrict__ rowptr, int* __restrict__ fill,
                       int* __restrict__ csr) {
    int e = blockIdx.x * blockDim.x + threadIdx.x;
    if (e >= NE) return;
    int d = dst[e];
    int p = atomicAdd(&fill[d], 1);
    csr[rowptr[d] + p] = src[e];
}

// ---------------- graph boundaries (batch sorted) ----------------
__global__ void k_starts(const int* __restrict__ batch, int* __restrict__ start) {
    int i = blockIdx.x * blockDim.x + threadIdx.x;
    if (i >= NN) return;
    int b = batch[i];
    if (i == 0) {
        for (int g = 0; g <= b; ++g) start[g] = 0;
    } else {
        int p = batch[i - 1];
        if (p != b) for (int g = p + 1; g <= b; ++g) start[g] = i;
    }
    if (i == NN - 1) {
        for (int g = b + 1; g <= NG; ++g) start[g] = NN;
    }
}

// ---------------- build hin layer0: [x | info[batch]] din=128 ----------------
__global__ void k_hin0(const float* __restrict__ x, const float* __restrict__ info,
                       const int* __restrict__ batch, float* __restrict__ hin) {
    int tid = blockIdx.x * blockDim.x + threadIdx.x;  // NN*32 float4 slots
    if (tid >= NN * 32) return;
    int i = tid >> 5;
    int c = (tid & 31) * 4;
    float4 v;
    if (c < DF) v = *(const float4*)&x[i * DF + c];
    else        v = *(const float4*)&info[batch[i] * DI + (c - DF)];
    *(float4*)&hin[i * 128 + c] = v;
}

// ---------------- build hin layers1/2: [hcat[:,off:off+128] | info] din=160 ----------------
__global__ void k_hin(const float* __restrict__ hcat, int off, const float* __restrict__ info,
                      const int* __restrict__ batch, float* __restrict__ hin) {
    int tid = blockIdx.x * blockDim.x + threadIdx.x;  // NN*40 float4 slots
    if (tid >= NN * 40) return;
    int i = tid / 40;
    int c = (tid % 40) * 4;
    float4 v;
    if (c < CO) v = *(const float4*)&hcat[i * HC + off + c];
    else        v = *(const float4*)&info[batch[i] * DI + (c - CO)];
    *(float4*)&hin[i * 160 + c] = v;
}

// ---------------- CSR gather-mean: mean[i] = avg_{s in N(i)} hin[s] ----------------
// one wave per node; lane l covers float2 slot l (128 floats), lanes 0..15 cover slots 64..79 (din=160)
template<int DIN>
__global__ __launch_bounds__(256) void k_gather(const float* __restrict__ hin,
                                                const int* __restrict__ rowptr,
                                                const int* __restrict__ csr,
                                                float* __restrict__ mean) {
    int wave = threadIdx.x >> 6;
    int lane = threadIdx.x & 63;
    int i = blockIdx.x * 4 + wave;
    if (i >= NN) return;
    int s0 = rowptr[i], s1 = rowptr[i + 1];
    float2 a0 = make_float2(0.f, 0.f);
    float2 a1 = make_float2(0.f, 0.f);
    int e = s0;
    for (; e + 1 < s1; e += 2) {
        int sA = csr[e], sB = csr[e + 1];
        const float2* hA = (const float2*)&hin[sA * DIN];
        const float2* hB = (const float2*)&hin[sB * DIN];
        float2 vA = hA[lane];
        float2 vB = hB[lane];
        a0.x += vA.x; a0.y += vA.y;
        a0.x += vB.x; a0.y += vB.y;
        if (DIN > 128 && lane < 16) {
            float2 wA = hA[64 + lane];
            float2 wB = hB[64 + lane];
            a1.x += wA.x; a1.y += wA.y;
            a1.x += wB.x; a1.y += wB.y;
        }
    }
    if (e < s1) {
        int sA = csr[e];
        const float2* hA = (const float2*)&hin[sA * DIN];
        float2 vA = hA[lane];
        a0.x += vA.x; a0.y += vA.y;
        if (DIN > 128 && lane < 16) {
            float2 wA = hA[64 + lane];
            a1.x += wA.x; a1.y += wA.y;
        }
    }
    float r = 1.0f / fmaxf((float)(s1 - s0), 1.0f);
    float2* mp = (float2*)&mean[i * DIN];
    mp[lane] = make_float2(a0.x * r, a0.y * r);
    if (DIN > 128 && lane < 16) mp[64 + lane] = make_float2(a1.x * r, a1.y * r);
}

// ---------------- dual GEMM: out = mean@Wl + b + hin@Wr -> hcat[:, colOff..colOff+128) ----------------
#define BM 16
#define KC 32
__global__ __launch_bounds__(256) void k_gemm(const float* __restrict__ mean, const float* __restrict__ hin,
                                              const float* __restrict__ Wl, const float* __restrict__ Wr,
                                              const float* __restrict__ bias,
                                              float* __restrict__ hcat, int colOff, int din) {
    __shared__ float s_wl[KC][CO];
    __shared__ float s_wr[KC][CO];
    __shared__ float s_am[BM][KC + 1];
    __shared__ float s_ah[BM][KC + 1];

    int tid = threadIdx.x;
    int row = tid >> 4;        // 0..15
    int cg  = tid & 15;        // col group
    int j0  = cg * 8;
    int i0  = blockIdx.x * BM;

    float acc[8];
#pragma unroll
    for (int c = 0; c < 8; ++c) acc[c] = bias[j0 + c];

    int nChunks = din / KC;
    for (int kc = 0; kc < nChunks; ++kc) {
        int k0 = kc * KC;
        __syncthreads();
        for (int t = tid; t < KC * CO / 4; t += 256) {
            int fi = t * 4;
            int k = fi >> 7;
            int j = fi & 127;
            *(float4*)&s_wl[k][j] = *(const float4*)&Wl[(k0 + k) * CO + j];
            *(float4*)&s_wr[k][j] = *(const float4*)&Wr[(k0 + k) * CO + j];
        }
        for (int t = tid; t < BM * KC; t += 256) {
            int r = t >> 5;
            int k = t & 31;
            int i = i0 + r;
            float av = 0.f, hv = 0.f;
            if (i < NN) {
                int gi = i * din + k0 + k;
                av = mean[gi];
                hv = hin[gi];
            }
            s_am[r][k] = av;
            s_ah[r][k] = hv;
        }
        __syncthreads();
#pragma unroll
        for (int k = 0; k < KC; ++k) {
            float am = s_am[row][k];
            float ah = s_ah[row][k];
            float4 wl0 = *(float4*)&s_wl[k][j0];
            float4 wl1 = *(float4*)&s_wl[k][j0 + 4];
            float4 wr0 = *(float4*)&s_wr[k][j0];
            float4 wr1 = *(float4*)&s_wr[k][j0 + 4];
            acc[0] += am * wl0.x + ah * wr0.x;
            acc[1] += am * wl0.y + ah * wr0.y;
            acc[2] += am * wl0.z + ah * wr0.z;
            acc[3] += am * wl0.w + ah * wr0.w;
            acc[4] += am * wl1.x + ah * wr1.x;
            acc[5] += am * wl1.y + ah * wr1.y;
            acc[6] += am * wl1.z + ah * wr1.z;
            acc[7] += am * wl1.w + ah * wr1.w;
        }
    }
    int i = i0 + row;
    if (i < NN) {
        *(float4*)&hcat[i * HC + colOff + j0]     = make_float4(acc[0], acc[1], acc[2], acc[3]);
        *(float4*)&hcat[i * HC + colOff + j0 + 4] = make_float4(acc[4], acc[5], acc[6], acc[7]);
    }
}

// ---------------- segment max pool over node ranges ----------------
__global__ void k_pool(const float* __restrict__ hcat, const int* __restrict__ start,
                       float* __restrict__ g) {
    int gr = blockIdx.x;
    int s = start[gr], e = start[gr + 1];
    for (int c = threadIdx.x; c < HC; c += blockDim.x) {
        float m = -FLT_MAX;
        for (int n = s; n < e; ++n) m = fmaxf(m, hcat[n * HC + c]);
        g[gr * HC + c] = m;
    }
}

// ---------------- FC head ----------------
__global__ __launch_bounds__(192) void k_fc(const float* __restrict__ g,
                                            const float* __restrict__ W1, const float* __restrict__ b1,
                                            const float* __restrict__ W2, const float* __restrict__ b2,
                                            float* __restrict__ out) {
    __shared__ float s_g[F1I];
    __shared__ float s_z[F1O];
    int gr = blockIdx.x;
    int tid = threadIdx.x;
    for (int k = tid; k < F1I; k += 192) s_g[k] = g[gr * F1I + k];
    __syncthreads();
    if (tid < F1O) {
        float acc = b1[tid];
        for (int k = 0; k < F1I; ++k) acc += s_g[k] * W1[k * F1O + tid];
        s_z[tid] = fmaxf(acc, 0.0f);
    }
    __syncthreads();
    if (tid < F2O) {
        float a = b2[tid];
        for (int k = 0; k < F1O; ++k) a += s_z[k] * W2[k * F2O + tid];
        out[gr * F2O + tid] = a;
    }
}

extern "C" void kernel_launch(void* const* d_in, const int* in_sizes, int n_in,
                              void* d_out, int out_size, void* d_ws, size_t ws_size,
                              hipStream_t stream) {
    const float* x     = (const float*)d_in[0];
    const int*   eidx  = (const int*)d_in[1];
    const int*   batch = (const int*)d_in[2];
    const float* info  = (const float*)d_in[3];
    const float* Wl[3] = {(const float*)d_in[4], (const float*)d_in[7], (const float*)d_in[10]};
    const float* Wr[3] = {(const float*)d_in[5], (const float*)d_in[8], (const float*)d_in[11]};
    const float* bs[3] = {(const float*)d_in[6], (const float*)d_in[9], (const float*)d_in[12]};
    const float* Wfc1  = (const float*)d_in[13];
    const float* bfc1  = (const float*)d_in[14];
    const float* Wfc2  = (const float*)d_in[15];
    const float* bfc2  = (const float*)d_in[16];
    float* out = (float*)d_out;

    const int* src = eidx;
    const int* dst = eidx + NE;

    // workspace layout (float/int32 units)
    float* ws = (float*)d_ws;
    float* hin    = ws;                        // NN*160            [0 .. 8,000,000)
    float* agg    = ws + 8000000;              // NN*160 (mean)
    float* hcat   = ws + 16000000;             // NN*384
    float* g      = ws + 35200000;             // NG*384
    int*   start  = (int*)(ws + 35392000);     // NG+1
    int*   rowptr = (int*)(ws + 35392512);     // NN+1
    int*   cnt    = (int*)(ws + 35442520);     // NN (histogram, then fill counters)
    int*   csr    = (int*)(ws + 35492528);     // NE

    // ---- CSR build (shared by all 3 layers) ----
    hipMemsetAsync(cnt, 0, NN * sizeof(int), stream);
    k_hist<<<(NE + 255) / 256, 256, 0, stream>>>(dst, cnt);
    k_scan<<<1, 1024, 0, stream>>>(cnt, rowptr);
    hipMemsetAsync(cnt, 0, NN * sizeof(int), stream);
    k_fill<<<(NE + 255) / 256, 256, 0, stream>>>(src, dst, rowptr, cnt, csr);
    k_starts<<<(NN + 255) / 256, 256, 0, stream>>>(batch, start);

    // ---- layer 0 (din=128) ----
    k_hin0<<<(NN * 32 + 255) / 256, 256, 0, stream>>>(x, info, batch, hin);
    k_gather<128><<<(NN + 3) / 4, 256, 0, stream>>>(hin, rowptr, csr, agg);
    k_gemm<<<(NN + BM - 1) / BM, 256, 0, stream>>>(agg, hin, Wl[0], Wr[0], bs[0], hcat, 0, 128);

    // ---- layer 1 (din=160) ----
    k_hin<<<(NN * 40 + 255) / 256, 256, 0, stream>>>(hcat, 0, info, batch, hin);
    k_gather<160><<<(NN + 3) / 4, 256, 0, stream>>>(hin, rowptr, csr, agg);
    k_gemm<<<(NN + BM - 1) / BM, 256, 0, stream>>>(agg, hin, Wl[1], Wr[1], bs[1], hcat, 128, 160);

    // ---- layer 2 (din=160) ----
    k_hin<<<(NN * 40 + 255) / 256, 256, 0, stream>>>(hcat, 128, info, batch, hin);
    k_gather<160><<<(NN + 3) / 4, 256, 0, stream>>>(hin, rowptr, csr, agg);
    k_gemm<<<(NN + BM - 1) / BM, 256, 0, stream>>>(agg, hin, Wl[2], Wr[2], bs[2], hcat, 256, 160);

    // ---- pool + head ----
    k_pool<<<NG, 128, 0, stream>>>(hcat, start, g);
    k_fc<<<NG, 192, 0, stream>>>(g, Wfc1, bfc1, Wfc2, bfc2, out);
}

// Round 3
// 563.379 us; speedup vs baseline: 9.6692x; 1.9153x over previous
//
#include <hip/hip_runtime.h>
#include <hip/hip_bf16.h>
#include <float.h>

#define NN 50000
#define NE 800000
#define DF 96
#define DI 32
#define CO 128          // conv out per layer
#define NG 500
#define HC 384
#define F1I 384
#define F1O 160
#define F2O 10

typedef unsigned int  u32;
typedef unsigned short u16;
typedef short bf16x8 __attribute__((ext_vector_type(8)));
typedef float f32x4  __attribute__((ext_vector_type(4)));

__device__ __forceinline__ u16 f2b(float f) {
    __hip_bfloat16 h = __float2bfloat16(f);
    return *reinterpret_cast<u16*>(&h);
}
__device__ __forceinline__ float b2f(u16 u) {
    return __uint_as_float(((u32)u) << 16);
}

// ---------------- CSR build ----------------
__global__ void k_hist(const int* __restrict__ dst, int* __restrict__ cnt) {
    int e = blockIdx.x * blockDim.x + threadIdx.x;
    if (e < NE) atomicAdd(&cnt[dst[e]], 1);
}

__global__ __launch_bounds__(1024) void k_scan(const int* __restrict__ cnt, int* __restrict__ rowptr) {
    __shared__ int s[1024];
    int tid = threadIdx.x;
    const int per = (NN + 1023) / 1024;
    int base = tid * per;
    int local = 0;
    for (int k = 0; k < per; ++k) {
        int i = base + k;
        if (i < NN) local += cnt[i];
    }
    s[tid] = local;
    __syncthreads();
    for (int off = 1; off < 1024; off <<= 1) {
        int t = (tid >= off) ? s[tid - off] : 0;
        __syncthreads();
        s[tid] += t;
        __syncthreads();
    }
    int running = s[tid] - local;
    for (int k = 0; k < per; ++k) {
        int i = base + k;
        if (i < NN) { rowptr[i] = running; running += cnt[i]; }
    }
    if (tid == 1023) rowptr[NN] = s[1023];
}

__global__ void k_fill(const int* __restrict__ src, const int* __restrict__ dst,
                       const int* __restrict__ rowptr, int* __restrict__ fill,
                       int* __restrict__ csr) {
    int e = blockIdx.x * blockDim.x + threadIdx.x;
    if (e >= NE) return;
    int d = dst[e];
    int p = atomicAdd(&fill[d], 1);
    csr[rowptr[d] + p] = src[e];
}

__global__ void k_starts(const int* __restrict__ batch, int* __restrict__ start) {
    int i = blockIdx.x * blockDim.x + threadIdx.x;
    if (i >= NN) return;
    int b = batch[i];
    if (i == 0) { for (int g = 0; g <= b; ++g) start[g] = 0; }
    else {
        int p = batch[i - 1];
        if (p != b) for (int g = p + 1; g <= b; ++g) start[g] = i;
    }
    if (i == NN - 1) { for (int g = b + 1; g <= NG; ++g) start[g] = NN; }
}

// ---------------- cast x -> bf16 ----------------
__global__ void k_cast_x(const float* __restrict__ x, u16* __restrict__ xb) {
    int tid = blockIdx.x * blockDim.x + threadIdx.x;   // NN*96/4 float4 slots
    if (tid >= NN * DF / 4) return;
    float4 v = *(const float4*)&x[tid * 4];
    ushort4 o;
    o.x = f2b(v.x); o.y = f2b(v.y); o.z = f2b(v.z); o.w = f2b(v.w);
    *(ushort4*)&xb[tid * 4] = o;
}

// ---------------- weight transpose -> WT[n][k] bf16, n in [0,256) ----------------
__global__ void k_wt(const float* __restrict__ Wl, const float* __restrict__ Wr,
                     u16* __restrict__ WTg, int K) {
    int tid = blockIdx.x * blockDim.x + threadIdx.x;
    if (tid >= 256 * K) return;
    int n = tid / K;
    int k = tid - n * K;
    float v = (n < CO) ? Wl[k * CO + n] : Wr[k * CO + (n - CO)];
    WTg[tid] = f2b(v);
}

// ---------------- info projections: infoQl = info@Wl_bot ; infoQr = info@Wr_bot + b ----------------
__global__ __launch_bounds__(256) void k_infow(const float* __restrict__ info,
                                               const float* __restrict__ Wl, const float* __restrict__ Wr,
                                               const float* __restrict__ bias, int Ktop,
                                               float* __restrict__ iQl, float* __restrict__ iQr) {
    int g = blockIdx.x;
    int c = threadIdx.x & 127;
    int sel = threadIdx.x >> 7;
    const float* W = sel ? Wr : Wl;
    float a = sel ? bias[c] : 0.0f;
    for (int d = 0; d < DI; ++d)
        a += info[g * DI + d] * W[(Ktop + d) * CO + c];
    (sel ? iQr : iQl)[g * CO + c] = a;
}

// ---------------- MFMA GEMM: Z[NN x 256] = A[NN x K] @ WT^T ----------------
template<int K>
__global__ __launch_bounds__(256) void k_mfma(const u16* __restrict__ A,
                                              const u16* __restrict__ WTg,
                                              u16* __restrict__ Z) {
    constexpr int PITCH = K + 8;
    __shared__ short lds[256 * PITCH];

    int tid  = threadIdx.x;
    int w    = tid >> 6;
    int lane = tid & 63;
    int quad = lane >> 4;
    int l15  = lane & 15;

    // stage all of WT into LDS (256 x K bf16, padded pitch)
    constexpr int CH = 256 * K / 8;     // 16B chunks
    const uint4* wp = (const uint4*)WTg;
    for (int c = tid; c < CH; c += 256) {
        int n  = c / (K / 8);
        int ko = (c - n * (K / 8)) * 8;
        *(uint4*)&lds[n * PITCH + ko] = wp[c];
    }
    __syncthreads();

    int i0 = blockIdx.x * 128 + w * 32;
    int r0 = i0 + l15;       if (r0 >= NN) r0 = NN - 1;
    int r1 = i0 + 16 + l15;  if (r1 >= NN) r1 = NN - 1;
    const short* A0 = (const short*)A + (size_t)r0 * K;
    const short* A1 = (const short*)A + (size_t)r1 * K;

    f32x4 acc[2][16];
#pragma unroll
    for (int rt = 0; rt < 2; ++rt)
#pragma unroll
        for (int ct = 0; ct < 16; ++ct)
            acc[rt][ct] = (f32x4){0.f, 0.f, 0.f, 0.f};

#pragma unroll
    for (int ks = 0; ks < K / 32; ++ks) {
        int ka = ks * 32 + quad * 8;
        bf16x8 a0 = *(const bf16x8*)(A0 + ka);
        bf16x8 a1 = *(const bf16x8*)(A1 + ka);
#pragma unroll
        for (int ct = 0; ct < 16; ++ct) {
            bf16x8 b = *(const bf16x8*)&lds[(ct * 16 + l15) * PITCH + ka];
            acc[0][ct] = __builtin_amdgcn_mfma_f32_16x16x32_bf16(a0, b, acc[0][ct], 0, 0, 0);
            acc[1][ct] = __builtin_amdgcn_mfma_f32_16x16x32_bf16(a1, b, acc[1][ct], 0, 0, 0);
        }
    }

    // store: D col = lane&15, row = quad*4 + reg
#pragma unroll
    for (int rt = 0; rt < 2; ++rt) {
#pragma unroll
        for (int reg = 0; reg < 4; ++reg) {
            int row = i0 + rt * 16 + quad * 4 + reg;
            if (row < NN) {
                u16* zp = &Z[(size_t)row * 256 + l15];
#pragma unroll
                for (int ct = 0; ct < 16; ++ct)
                    zp[ct * 16] = f2b(acc[rt][ct][reg]);
            }
        }
    }
}

// ---------------- combine: zlp = Zl + iQl[batch]; zq = Zr + iQr[batch] ----------------
__global__ void k_combine(const u32* __restrict__ Z, const int* __restrict__ batch,
                          const float* __restrict__ iQl, const float* __restrict__ iQr,
                          u32* __restrict__ zlp, u32* __restrict__ zq) {
    int tid = blockIdx.x * blockDim.x + threadIdx.x;   // NN*128 uint slots
    if (tid >= NN * 128) return;
    int i  = tid >> 7;
    int c2 = tid & 127;
    int b  = batch[i];
    u32 u = Z[tid];
    float lo = __uint_as_float(u << 16);
    float hi = __uint_as_float(u & 0xffff0000u);
    if (c2 < 64) {
        lo += iQl[b * CO + 2 * c2];
        hi += iQl[b * CO + 2 * c2 + 1];
        zlp[i * 64 + c2] = (u32)f2b(lo) | ((u32)f2b(hi) << 16);
    } else {
        int c = 2 * c2 - 128;
        lo += iQr[b * CO + c];
        hi += iQr[b * CO + c + 1];
        zq[i * 64 + (c2 - 64)] = (u32)f2b(lo) | ((u32)f2b(hi) << 16);
    }
}

// ---------------- gather-mean (bf16 rows, fp32 accum): h = mean(zlp[nbrs]) + zq ----------------
__global__ __launch_bounds__(256) void k_gatherb(const u32* __restrict__ zlp, const u32* __restrict__ zq,
                                                 const int* __restrict__ rowptr, const int* __restrict__ csr,
                                                 u32* __restrict__ hout) {
    int wave = threadIdx.x >> 6;
    int lane = threadIdx.x & 63;
    int i = blockIdx.x * 4 + wave;
    if (i >= NN) return;
    int s0 = rowptr[i], s1 = rowptr[i + 1];
    float a0 = 0.f, a1 = 0.f;
    int e = s0;
    for (; e + 1 < s1; e += 2) {
        int sA = csr[e], sB = csr[e + 1];
        u32 uA = zlp[sA * 64 + lane];
        u32 uB = zlp[sB * 64 + lane];
        a0 += __uint_as_float(uA << 16);
        a1 += __uint_as_float(uA & 0xffff0000u);
        a0 += __uint_as_float(uB << 16);
        a1 += __uint_as_float(uB & 0xffff0000u);
    }
    if (e < s1) {
        u32 uA = zlp[csr[e] * 64 + lane];
        a0 += __uint_as_float(uA << 16);
        a1 += __uint_as_float(uA & 0xffff0000u);
    }
    float r = 1.0f / fmaxf((float)(s1 - s0), 1.0f);
    u32 q = zq[i * 64 + lane];
    float h0 = a0 * r + __uint_as_float(q << 16);
    float h1 = a1 * r + __uint_as_float(q & 0xffff0000u);
    hout[i * 64 + lane] = (u32)f2b(h0) | ((u32)f2b(h1) << 16);
}

// ---------------- pool: segment max over 3 bf16 h-buffers ----------------
__global__ __launch_bounds__(384) void k_pool(const u16* __restrict__ h1, const u16* __restrict__ h2,
                                              const u16* __restrict__ h3, const int* __restrict__ start,
                                              float* __restrict__ g) {
    int gr = blockIdx.x;
    int c  = threadIdx.x;           // 0..383
    int sel = c >> 7;
    int cc  = c & 127;
    const u16* hb = (sel == 0) ? h1 : (sel == 1) ? h2 : h3;
    int s = start[gr], e = start[gr + 1];
    float m = -FLT_MAX;
    for (int n = s; n < e; ++n) m = fmaxf(m, b2f(hb[n * 128 + cc]));
    g[gr * HC + c] = m;
}

// ---------------- FC head ----------------
__global__ __launch_bounds__(192) void k_fc(const float* __restrict__ g,
                                            const float* __restrict__ W1, const float* __restrict__ b1,
                                            const float* __restrict__ W2, const float* __restrict__ b2,
                                            float* __restrict__ out) {
    __shared__ float s_g[F1I];
    __shared__ float s_z[F1O];
    int gr = blockIdx.x;
    int tid = threadIdx.x;
    for (int k = tid; k < F1I; k += 192) s_g[k] = g[gr * F1I + k];
    __syncthreads();
    if (tid < F1O) {
        float acc = b1[tid];
        for (int k = 0; k < F1I; ++k) acc += s_g[k] * W1[k * F1O + tid];
        s_z[tid] = fmaxf(acc, 0.0f);
    }
    __syncthreads();
    if (tid < F2O) {
        float a = b2[tid];
        for (int k = 0; k < F1O; ++k) a += s_z[k] * W2[k * F2O + tid];
        out[gr * F2O + tid] = a;
    }
}

extern "C" void kernel_launch(void* const* d_in, const int* in_sizes, int n_in,
                              void* d_out, int out_size, void* d_ws, size_t ws_size,
                              hipStream_t stream) {
    const float* x     = (const float*)d_in[0];
    const int*   eidx  = (const int*)d_in[1];
    const int*   batch = (const int*)d_in[2];
    const float* info  = (const float*)d_in[3];
    const float* Wl[3] = {(const float*)d_in[4], (const float*)d_in[7], (const float*)d_in[10]};
    const float* Wr[3] = {(const float*)d_in[5], (const float*)d_in[8], (const float*)d_in[11]};
    const float* bs[3] = {(const float*)d_in[6], (const float*)d_in[9], (const float*)d_in[12]};
    const float* Wfc1  = (const float*)d_in[13];
    const float* bfc1  = (const float*)d_in[14];
    const float* Wfc2  = (const float*)d_in[15];
    const float* bfc2  = (const float*)d_in[16];
    float* out = (float*)d_out;

    const int* src = eidx;
    const int* dst = eidx + NE;

    // workspace layout (byte offsets, all 16B-aligned)
    char* W = (char*)d_ws;
    u16* xb    = (u16*)(W + 0);             // 50000*96  bf16
    u16* h1    = (u16*)(W + 9600000);       // 50000*128 bf16
    u16* h2    = (u16*)(W + 22400000);
    u16* h3    = (u16*)(W + 35200000);
    u16* Z     = (u16*)(W + 48000000);      // 50000*256 bf16
    u32* zlp   = (u32*)(W + 73600000);      // 50000*128 bf16 (as uints)
    u32* zq    = (u32*)(W + 86400000);
    u16* WT0   = (u16*)(W + 99200000);      // 256*96
    u16* WT1   = (u16*)(W + 99249152);      // 256*128
    u16* WT2   = (u16*)(W + 99314688);
    float* iQl0 = (float*)(W + 99380224);   // 500*128 f32 each
    float* iQr0 = (float*)(W + 99636224);
    float* iQl1 = (float*)(W + 99892224);
    float* iQr1 = (float*)(W + 100148224);
    float* iQl2 = (float*)(W + 100404224);
    float* iQr2 = (float*)(W + 100660224);
    float* g    = (float*)(W + 100916224);  // 500*384 f32
    int* start  = (int*)(W + 101684224);    // NG+1
    int* rowptr = (int*)(W + 101686272);    // NN+1
    int* cnt    = (int*)(W + 101886288);    // NN
    int* csr    = (int*)(W + 102086288);    // NE

    // ---- CSR + starts + casts + weight prep ----
    hipMemsetAsync(cnt, 0, NN * sizeof(int), stream);
    k_hist<<<(NE + 255) / 256, 256, 0, stream>>>(dst, cnt);
    k_scan<<<1, 1024, 0, stream>>>(cnt, rowptr);
    hipMemsetAsync(cnt, 0, NN * sizeof(int), stream);
    k_fill<<<(NE + 255) / 256, 256, 0, stream>>>(src, dst, rowptr, cnt, csr);
    k_starts<<<(NN + 255) / 256, 256, 0, stream>>>(batch, start);

    k_cast_x<<<(NN * DF / 4 + 255) / 256, 256, 0, stream>>>(x, xb);
    k_wt<<<(256 * 96  + 255) / 256, 256, 0, stream>>>(Wl[0], Wr[0], WT0, 96);
    k_wt<<<(256 * 128 + 255) / 256, 256, 0, stream>>>(Wl[1], Wr[1], WT1, 128);
    k_wt<<<(256 * 128 + 255) / 256, 256, 0, stream>>>(Wl[2], Wr[2], WT2, 128);
    k_infow<<<NG, 256, 0, stream>>>(info, Wl[0], Wr[0], bs[0], 96,  iQl0, iQr0);
    k_infow<<<NG, 256, 0, stream>>>(info, Wl[1], Wr[1], bs[1], 128, iQl1, iQr1);
    k_infow<<<NG, 256, 0, stream>>>(info, Wl[2], Wr[2], bs[2], 128, iQl2, iQr2);

    const int gGemm = (NN + 127) / 128;
    const int gComb = (NN * 128 + 255) / 256;
    const int gGath = (NN + 3) / 4;

    // ---- layer 0 ----
    k_mfma<96><<<gGemm, 256, 0, stream>>>(xb, WT0, Z);
    k_combine<<<gComb, 256, 0, stream>>>((const u32*)Z, batch, iQl0, iQr0, zlp, zq);
    k_gatherb<<<gGath, 256, 0, stream>>>(zlp, zq, rowptr, csr, (u32*)h1);

    // ---- layer 1 ----
    k_mfma<128><<<gGemm, 256, 0, stream>>>(h1, WT1, Z);
    k_combine<<<gComb, 256, 0, stream>>>((const u32*)Z, batch, iQl1, iQr1, zlp, zq);
    k_gatherb<<<gGath, 256, 0, stream>>>(zlp, zq, rowptr, csr, (u32*)h2);

    // ---- layer 2 ----
    k_mfma<128><<<gGemm, 256, 0, stream>>>(h2, WT2, Z);
    k_combine<<<gComb, 256, 0, stream>>>((const u32*)Z, batch, iQl2, iQr2, zlp, zq);
    k_gatherb<<<gGath, 256, 0, stream>>>(zlp, zq, rowptr, csr, (u32*)h3);

    // ---- pool + head ----
    k_pool<<<NG, 384, 0, stream>>>(h1, h2, h3, start, g);
    k_fc<<<NG, 192, 0, stream>>>(g, Wfc1, bfc1, Wfc2, bfc2, out);
}

// Round 4
// 412.597 us; speedup vs baseline: 13.2028x; 1.3654x over previous
//
#include <hip/hip_runtime.h>
#include <hip/hip_bf16.h>
#include <float.h>

#define NN 50000
#define NE 800000
#define DF 96
#define DI 32
#define CO 128          // conv out per layer
#define NG 500
#define HC 384
#define F1I 384
#define F1O 160
#define F2O 10
#define NBLK 196        // ceil(NN/256)

typedef unsigned int  u32;
typedef unsigned short u16;
typedef short bf16x8 __attribute__((ext_vector_type(8)));
typedef float f32x4  __attribute__((ext_vector_type(4)));

__device__ __forceinline__ u16 f2b(float f) {
    __hip_bfloat16 h = __float2bfloat16(f);
    return *reinterpret_cast<u16*>(&h);
}
__device__ __forceinline__ float b2f(u16 u) {
    return __uint_as_float(((u32)u) << 16);
}

// ---------------- CSR build: histogram ----------------
__global__ void k_hist(const int* __restrict__ dst, int* __restrict__ cnt) {
    int e = blockIdx.x * blockDim.x + threadIdx.x;
    if (e < NE) atomicAdd(&cnt[dst[e]], 1);
}

// ---------------- multi-block scan ----------------
__global__ __launch_bounds__(256) void k_bsum(const int* __restrict__ cnt, int* __restrict__ bsum) {
    __shared__ int s[256];
    int i = blockIdx.x * 256 + threadIdx.x;
    s[threadIdx.x] = (i < NN) ? cnt[i] : 0;
    __syncthreads();
    for (int off = 128; off > 0; off >>= 1) {
        if (threadIdx.x < off) s[threadIdx.x] += s[threadIdx.x + off];
        __syncthreads();
    }
    if (threadIdx.x == 0) bsum[blockIdx.x] = s[0];
}

__global__ __launch_bounds__(256) void k_scanb(const int* __restrict__ bsum, int* __restrict__ bpre) {
    __shared__ int s[256];
    int tid = threadIdx.x;
    int v = (tid < NBLK) ? bsum[tid] : 0;
    s[tid] = v;
    __syncthreads();
    for (int off = 1; off < 256; off <<= 1) {
        int t = (tid >= off) ? s[tid - off] : 0;
        __syncthreads();
        s[tid] += t;
        __syncthreads();
    }
    if (tid < NBLK) bpre[tid] = s[tid] - v;
}

__global__ __launch_bounds__(256) void k_rowptr(const int* __restrict__ cnt, const int* __restrict__ bpre,
                                                int* __restrict__ rowptr) {
    __shared__ int s[256];
    int tid = threadIdx.x;
    int i = blockIdx.x * 256 + tid;
    int v = (i < NN) ? cnt[i] : 0;
    s[tid] = v;
    __syncthreads();
    for (int off = 1; off < 256; off <<= 1) {
        int t = (tid >= off) ? s[tid - off] : 0;
        __syncthreads();
        s[tid] += t;
        __syncthreads();
    }
    int pre = bpre[blockIdx.x] + s[tid] - v;
    if (i < NN) rowptr[i] = pre;
    if (i == NN - 1) rowptr[NN] = pre + v;
}

// ---------------- bucket fill ----------------
__global__ void k_fill(const int* __restrict__ src, const int* __restrict__ dst,
                       const int* __restrict__ rowptr, int* __restrict__ fill,
                       int* __restrict__ csr) {
    int e = blockIdx.x * blockDim.x + threadIdx.x;
    if (e >= NE) return;
    int d = dst[e];
    int p = atomicAdd(&fill[d], 1);
    csr[rowptr[d] + p] = src[e];
}

// ---------------- graph boundaries (batch sorted) ----------------
__global__ void k_starts(const int* __restrict__ batch, int* __restrict__ start) {
    int i = blockIdx.x * blockDim.x + threadIdx.x;
    if (i >= NN) return;
    int b = batch[i];
    if (i == 0) { for (int g = 0; g <= b; ++g) start[g] = 0; }
    else {
        int p = batch[i - 1];
        if (p != b) for (int g = p + 1; g <= b; ++g) start[g] = i;
    }
    if (i == NN - 1) { for (int g = b + 1; g <= NG; ++g) start[g] = NN; }
}

// ---------------- cast x -> bf16 ----------------
__global__ void k_cast_x(const float* __restrict__ x, u16* __restrict__ xb) {
    int tid = blockIdx.x * blockDim.x + threadIdx.x;
    if (tid >= NN * DF / 4) return;
    float4 v = *(const float4*)&x[tid * 4];
    ushort4 o;
    o.x = f2b(v.x); o.y = f2b(v.y); o.z = f2b(v.z); o.w = f2b(v.w);
    *(ushort4*)&xb[tid * 4] = o;
}

// ---------------- weight transpose -> WT[n][k] bf16, n in [0,256) ----------------
__global__ void k_wt(const float* __restrict__ Wl, const float* __restrict__ Wr,
                     u16* __restrict__ WTg, int K) {
    int tid = blockIdx.x * blockDim.x + threadIdx.x;
    if (tid >= 256 * K) return;
    int n = tid / K;
    int k = tid - n * K;
    float v = (n < CO) ? Wl[k * CO + n] : Wr[k * CO + (n - CO)];
    WTg[tid] = f2b(v);
}

// ---------------- info projections ----------------
__global__ __launch_bounds__(256) void k_infow(const float* __restrict__ info,
                                               const float* __restrict__ Wl, const float* __restrict__ Wr,
                                               const float* __restrict__ bias, int Ktop,
                                               float* __restrict__ iQl, float* __restrict__ iQr) {
    int g = blockIdx.x;
    int c = threadIdx.x & 127;
    int sel = threadIdx.x >> 7;
    const float* W = sel ? Wr : Wl;
    float a = sel ? bias[c] : 0.0f;
    for (int d = 0; d < DI; ++d)
        a += info[g * DI + d] * W[(Ktop + d) * CO + c];
    (sel ? iQr : iQl)[g * CO + c] = a;
}

// ---------------- MFMA GEMM + fused combine ----------------
// zlp[row][0..127] = (A@Wl_top)[row] + iQl[batch[row]]
// zq [row][0..127] = (A@Wr_top)[row] + iQr[batch[row]]   (bias folded into iQr)
template<int K>
__global__ __launch_bounds__(256) void k_mfma(const u16* __restrict__ A,
                                              const u16* __restrict__ WTg,
                                              const int* __restrict__ batch,
                                              const float* __restrict__ iQl,
                                              const float* __restrict__ iQr,
                                              u16* __restrict__ zlp,
                                              u16* __restrict__ zq) {
    constexpr int PITCH = K + 8;
    __shared__ short lds[256 * PITCH];

    int tid  = threadIdx.x;
    int w    = tid >> 6;
    int lane = tid & 63;
    int quad = lane >> 4;
    int l15  = lane & 15;

    constexpr int CH = 256 * K / 8;
    const uint4* wp = (const uint4*)WTg;
    for (int c = tid; c < CH; c += 256) {
        int n  = c / (K / 8);
        int ko = (c - n * (K / 8)) * 8;
        *(uint4*)&lds[n * PITCH + ko] = wp[c];
    }
    __syncthreads();

    int i0 = blockIdx.x * 128 + w * 32;
    int r0 = i0 + l15;       if (r0 >= NN) r0 = NN - 1;
    int r1 = i0 + 16 + l15;  if (r1 >= NN) r1 = NN - 1;
    const short* A0 = (const short*)A + (size_t)r0 * K;
    const short* A1 = (const short*)A + (size_t)r1 * K;

    f32x4 acc[2][16];
#pragma unroll
    for (int rt = 0; rt < 2; ++rt)
#pragma unroll
        for (int ct = 0; ct < 16; ++ct)
            acc[rt][ct] = (f32x4){0.f, 0.f, 0.f, 0.f};

#pragma unroll
    for (int ks = 0; ks < K / 32; ++ks) {
        int ka = ks * 32 + quad * 8;
        bf16x8 a0 = *(const bf16x8*)(A0 + ka);
        bf16x8 a1 = *(const bf16x8*)(A1 + ka);
#pragma unroll
        for (int ct = 0; ct < 16; ++ct) {
            bf16x8 b = *(const bf16x8*)&lds[(ct * 16 + l15) * PITCH + ka];
            acc[0][ct] = __builtin_amdgcn_mfma_f32_16x16x32_bf16(a0, b, acc[0][ct], 0, 0, 0);
            acc[1][ct] = __builtin_amdgcn_mfma_f32_16x16x32_bf16(a1, b, acc[1][ct], 0, 0, 0);
        }
    }

    // epilogue: D col = l15 + ct*16, row = quad*4 + reg; fuse +iQ and write zlp/zq
#pragma unroll
    for (int rt = 0; rt < 2; ++rt) {
#pragma unroll
        for (int reg = 0; reg < 4; ++reg) {
            int row = i0 + rt * 16 + quad * 4 + reg;
            if (row < NN) {
                int b = batch[row];
                const float* ql = &iQl[b * CO];
                const float* qr = &iQr[b * CO];
                u16* lp = zlp + (size_t)row * CO;
                u16* qp = zq  + (size_t)row * CO;
#pragma unroll
                for (int ct = 0; ct < 8; ++ct) {
                    int col = ct * 16 + l15;
                    lp[col] = f2b(acc[rt][ct][reg] + ql[col]);
                }
#pragma unroll
                for (int ct = 8; ct < 16; ++ct) {
                    int col = ct * 16 + l15 - 128;
                    qp[col] = f2b(acc[rt][ct][reg] + qr[col]);
                }
            }
        }
    }
}

// ---------------- gather-mean (bf16 rows, fp32 accum): h = mean(zlp[nbrs]) + zq ----------------
__global__ __launch_bounds__(256) void k_gatherb(const u32* __restrict__ zlp, const u32* __restrict__ zq,
                                                 const int* __restrict__ rowptr, const int* __restrict__ csr,
                                                 u32* __restrict__ hout) {
    int wave = threadIdx.x >> 6;
    int lane = threadIdx.x & 63;
    int i = blockIdx.x * 4 + wave;
    if (i >= NN) return;
    int s0 = rowptr[i], s1 = rowptr[i + 1];
    float a0 = 0.f, a1 = 0.f, c0 = 0.f, c1 = 0.f;
    int e = s0;
    for (; e + 3 < s1; e += 4) {
        int sA = csr[e], sB = csr[e + 1], sC = csr[e + 2], sD = csr[e + 3];
        u32 uA = zlp[sA * 64 + lane];
        u32 uB = zlp[sB * 64 + lane];
        u32 uC = zlp[sC * 64 + lane];
        u32 uD = zlp[sD * 64 + lane];
        a0 += __uint_as_float(uA << 16) + __uint_as_float(uB << 16);
        a1 += __uint_as_float(uA & 0xffff0000u) + __uint_as_float(uB & 0xffff0000u);
        c0 += __uint_as_float(uC << 16) + __uint_as_float(uD << 16);
        c1 += __uint_as_float(uC & 0xffff0000u) + __uint_as_float(uD & 0xffff0000u);
    }
    for (; e < s1; ++e) {
        u32 uA = zlp[csr[e] * 64 + lane];
        a0 += __uint_as_float(uA << 16);
        a1 += __uint_as_float(uA & 0xffff0000u);
    }
    a0 += c0; a1 += c1;
    float r = 1.0f / fmaxf((float)(s1 - s0), 1.0f);
    u32 q = zq[i * 64 + lane];
    float h0 = a0 * r + __uint_as_float(q << 16);
    float h1 = a1 * r + __uint_as_float(q & 0xffff0000u);
    hout[i * 64 + lane] = (u32)f2b(h0) | ((u32)f2b(h1) << 16);
}

// ---------------- pool: segment max over 3 bf16 h-buffers ----------------
__global__ __launch_bounds__(384) void k_pool(const u16* __restrict__ h1, const u16* __restrict__ h2,
                                              const u16* __restrict__ h3, const int* __restrict__ start,
                                              float* __restrict__ g) {
    int gr = blockIdx.x;
    int c  = threadIdx.x;
    int sel = c >> 7;
    int cc  = c & 127;
    const u16* hb = (sel == 0) ? h1 : (sel == 1) ? h2 : h3;
    int s = start[gr], e = start[gr + 1];
    float m0 = -FLT_MAX, m1 = -FLT_MAX;
    int n = s;
    for (; n + 1 < e; n += 2) {
        m0 = fmaxf(m0, b2f(hb[n * 128 + cc]));
        m1 = fmaxf(m1, b2f(hb[(n + 1) * 128 + cc]));
    }
    if (n < e) m0 = fmaxf(m0, b2f(hb[n * 128 + cc]));
    g[gr * HC + c] = fmaxf(m0, m1);
}

// ---------------- FC head ----------------
__global__ __launch_bounds__(192) void k_fc(const float* __restrict__ g,
                                            const float* __restrict__ W1, const float* __restrict__ b1,
                                            const float* __restrict__ W2, const float* __restrict__ b2,
                                            float* __restrict__ out) {
    __shared__ float s_g[F1I];
    __shared__ float s_z[F1O];
    int gr = blockIdx.x;
    int tid = threadIdx.x;
    for (int k = tid; k < F1I; k += 192) s_g[k] = g[gr * F1I + k];
    __syncthreads();
    if (tid < F1O) {
        float acc = b1[tid];
        for (int k = 0; k < F1I; ++k) acc += s_g[k] * W1[k * F1O + tid];
        s_z[tid] = fmaxf(acc, 0.0f);
    }
    __syncthreads();
    if (tid < F2O) {
        float a = b2[tid];
        for (int k = 0; k < F1O; ++k) a += s_z[k] * W2[k * F2O + tid];
        out[gr * F2O + tid] = a;
    }
}

extern "C" void kernel_launch(void* const* d_in, const int* in_sizes, int n_in,
                              void* d_out, int out_size, void* d_ws, size_t ws_size,
                              hipStream_t stream) {
    const float* x     = (const float*)d_in[0];
    const int*   eidx  = (const int*)d_in[1];
    const int*   batch = (const int*)d_in[2];
    const float* info  = (const float*)d_in[3];
    const float* Wl[3] = {(const float*)d_in[4], (const float*)d_in[7], (const float*)d_in[10]};
    const float* Wr[3] = {(const float*)d_in[5], (const float*)d_in[8], (const float*)d_in[11]};
    const float* bs[3] = {(const float*)d_in[6], (const float*)d_in[9], (const float*)d_in[12]};
    const float* Wfc1  = (const float*)d_in[13];
    const float* bfc1  = (const float*)d_in[14];
    const float* Wfc2  = (const float*)d_in[15];
    const float* bfc2  = (const float*)d_in[16];
    float* out = (float*)d_out;

    const int* src = eidx;
    const int* dst = eidx + NE;

    // workspace layout (byte offsets, 16B-aligned)
    char* W = (char*)d_ws;
    u16* xb     = (u16*)(W + 0);             // 50000*96 bf16
    u16* h1     = (u16*)(W + 9600000);       // 50000*128 bf16 each
    u16* h2     = (u16*)(W + 22400000);
    u16* h3     = (u16*)(W + 35200000);
    u16* zlp    = (u16*)(W + 48000000);      // 50000*128 bf16
    u16* zq     = (u16*)(W + 60800000);
    u16* WT0    = (u16*)(W + 73600000);      // 256*96
    u16* WT1    = (u16*)(W + 73649152);      // 256*128
    u16* WT2    = (u16*)(W + 73714688);
    float* iQl0 = (float*)(W + 73780224);    // 500*128 f32 each
    float* iQr0 = (float*)(W + 74036224);
    float* iQl1 = (float*)(W + 74292224);
    float* iQr1 = (float*)(W + 74548224);
    float* iQl2 = (float*)(W + 74804224);
    float* iQr2 = (float*)(W + 75060224);
    float* g    = (float*)(W + 75316224);    // 500*384 f32
    int* start  = (int*)(W + 76084224);      // NG+1
    int* rowptr = (int*)(W + 76086272);      // NN+1
    int* cnt    = (int*)(W + 76286288);      // NN
    int* csr    = (int*)(W + 76486288);      // NE
    int* bsum   = (int*)(W + 79686288);      // NBLK
    int* bpre   = (int*)(W + 79687312);      // NBLK

    // ---- CSR + starts + casts + weight prep ----
    hipMemsetAsync(cnt, 0, NN * sizeof(int), stream);
    k_hist<<<(NE + 255) / 256, 256, 0, stream>>>(dst, cnt);
    k_bsum<<<NBLK, 256, 0, stream>>>(cnt, bsum);
    k_scanb<<<1, 256, 0, stream>>>(bsum, bpre);
    k_rowptr<<<NBLK, 256, 0, stream>>>(cnt, bpre, rowptr);
    hipMemsetAsync(cnt, 0, NN * sizeof(int), stream);
    k_fill<<<(NE + 255) / 256, 256, 0, stream>>>(src, dst, rowptr, cnt, csr);
    k_starts<<<(NN + 255) / 256, 256, 0, stream>>>(batch, start);

    k_cast_x<<<(NN * DF / 4 + 255) / 256, 256, 0, stream>>>(x, xb);
    k_wt<<<(256 * 96  + 255) / 256, 256, 0, stream>>>(Wl[0], Wr[0], WT0, 96);
    k_wt<<<(256 * 128 + 255) / 256, 256, 0, stream>>>(Wl[1], Wr[1], WT1, 128);
    k_wt<<<(256 * 128 + 255) / 256, 256, 0, stream>>>(Wl[2], Wr[2], WT2, 128);
    k_infow<<<NG, 256, 0, stream>>>(info, Wl[0], Wr[0], bs[0], 96,  iQl0, iQr0);
    k_infow<<<NG, 256, 0, stream>>>(info, Wl[1], Wr[1], bs[1], 128, iQl1, iQr1);
    k_infow<<<NG, 256, 0, stream>>>(info, Wl[2], Wr[2], bs[2], 128, iQl2, iQr2);

    const int gGemm = (NN + 127) / 128;
    const int gGath = (NN + 3) / 4;

    // ---- layer 0 ----
    k_mfma<96><<<gGemm, 256, 0, stream>>>(xb, WT0, batch, iQl0, iQr0, zlp, zq);
    k_gatherb<<<gGath, 256, 0, stream>>>((const u32*)zlp, (const u32*)zq, rowptr, csr, (u32*)h1);

    // ---- layer 1 ----
    k_mfma<128><<<gGemm, 256, 0, stream>>>(h1, WT1, batch, iQl1, iQr1, zlp, zq);
    k_gatherb<<<gGath, 256, 0, stream>>>((const u32*)zlp, (const u32*)zq, rowptr, csr, (u32*)h2);

    // ---- layer 2 ----
    k_mfma<128><<<gGemm, 256, 0, stream>>>(h2, WT2, batch, iQl2, iQr2, zlp, zq);
    k_gatherb<<<gGath, 256, 0, stream>>>((const u32*)zlp, (const u32*)zq, rowptr, csr, (u32*)h3);

    // ---- pool + head ----
    k_pool<<<NG, 384, 0, stream>>>(h1, h2, h3, start, g);
    k_fc<<<NG, 192, 0, stream>>>(g, Wfc1, bfc1, Wfc2, bfc2, out);
}

// Round 5
// 367.709 us; speedup vs baseline: 14.8145x; 1.1221x over previous
//
#include <hip/hip_runtime.h>
#include <hip/hip_bf16.h>
#include <float.h>

#define NN 50000
#define NE 800000
#define DF 96
#define DI 32
#define CO 128          // conv out per layer
#define NG 500
#define HC 384
#define F1I 384
#define F1O 160
#define F2O 10
#define NBLK 196        // ceil(NN/256)

typedef unsigned int  u32;
typedef unsigned short u16;
typedef short bf16x8 __attribute__((ext_vector_type(8)));
typedef float f32x4  __attribute__((ext_vector_type(4)));

__device__ __forceinline__ u16 f2b(float f) {
    __hip_bfloat16 h = __float2bfloat16(f);
    return *reinterpret_cast<u16*>(&h);
}
__device__ __forceinline__ float b2f(u16 u) {
    return __uint_as_float(((u32)u) << 16);
}
__device__ __forceinline__ float blo(u32 u) { return __uint_as_float(u << 16); }
__device__ __forceinline__ float bhi(u32 u) { return __uint_as_float(u & 0xffff0000u); }

// ================= fused prep: zero cnt | starts | cast x | wt x3 | infow x3 =================
#define PB_CNT    196
#define PB_STARTS 196
#define PB_CAST   4688   // NN*96/4 = 1,200,000 threads
#define PB_WT0    96     // 256*96
#define PB_WT1    128    // 256*128
#define PB_WT2    128
#define PB_INFO   500
#define PREP_GRID (PB_CNT + PB_STARTS + PB_CAST + PB_WT0 + PB_WT1 + PB_WT2 + 3 * PB_INFO)

__global__ __launch_bounds__(256) void k_prep(
        const float* __restrict__ x, const int* __restrict__ batch, const float* __restrict__ info,
        const float* __restrict__ Wl0, const float* __restrict__ Wr0, const float* __restrict__ b0,
        const float* __restrict__ Wl1, const float* __restrict__ Wr1, const float* __restrict__ b1,
        const float* __restrict__ Wl2, const float* __restrict__ Wr2, const float* __restrict__ b2,
        int* __restrict__ cnt, int* __restrict__ start, u16* __restrict__ xb,
        u16* __restrict__ WT0, u16* __restrict__ WT1, u16* __restrict__ WT2,
        float* __restrict__ iQl0, float* __restrict__ iQr0,
        float* __restrict__ iQl1, float* __restrict__ iQr1,
        float* __restrict__ iQl2, float* __restrict__ iQr2) {
    int blk = blockIdx.x;
    int t = threadIdx.x;
    if (blk < PB_CNT) {                                   // zero cnt
        int i = blk * 256 + t;
        if (i < NN) cnt[i] = 0;
        return;
    }
    blk -= PB_CNT;
    if (blk < PB_STARTS) {                                // graph boundaries
        int i = blk * 256 + t;
        if (i >= NN) return;
        int b = batch[i];
        if (i == 0) { for (int g = 0; g <= b; ++g) start[g] = 0; }
        else {
            int p = batch[i - 1];
            if (p != b) for (int g = p + 1; g <= b; ++g) start[g] = i;
        }
        if (i == NN - 1) { for (int g = b + 1; g <= NG; ++g) start[g] = NN; }
        return;
    }
    blk -= PB_STARTS;
    if (blk < PB_CAST) {                                  // x -> bf16
        int tid = blk * 256 + t;
        if (tid >= NN * DF / 4) return;
        float4 v = *(const float4*)&x[tid * 4];
        ushort4 o;
        o.x = f2b(v.x); o.y = f2b(v.y); o.z = f2b(v.z); o.w = f2b(v.w);
        *(ushort4*)&xb[tid * 4] = o;
        return;
    }
    blk -= PB_CAST;
    if (blk < PB_WT0 + PB_WT1 + PB_WT2) {                 // weight transposes
        const float* Wl; const float* Wr; u16* WT; int K; int rel;
        if (blk < PB_WT0) { Wl = Wl0; Wr = Wr0; WT = WT0; K = 96;  rel = blk; }
        else if (blk < PB_WT0 + PB_WT1) { Wl = Wl1; Wr = Wr1; WT = WT1; K = 128; rel = blk - PB_WT0; }
        else { Wl = Wl2; Wr = Wr2; WT = WT2; K = 128; rel = blk - PB_WT0 - PB_WT1; }
        int tid = rel * 256 + t;
        if (tid >= 256 * K) return;
        int n = tid / K;
        int k = tid - n * K;
        float v = (n < CO) ? Wl[k * CO + n] : Wr[k * CO + (n - CO)];
        WT[tid] = f2b(v);
        return;
    }
    blk -= PB_WT0 + PB_WT1 + PB_WT2;
    {                                                     // info projections
        const float* Wl; const float* Wr; const float* bias; float* iQl; float* iQr; int Ktop; int g;
        if (blk < PB_INFO) { Wl = Wl0; Wr = Wr0; bias = b0; iQl = iQl0; iQr = iQr0; Ktop = 96;  g = blk; }
        else if (blk < 2 * PB_INFO) { Wl = Wl1; Wr = Wr1; bias = b1; iQl = iQl1; iQr = iQr1; Ktop = 128; g = blk - PB_INFO; }
        else { Wl = Wl2; Wr = Wr2; bias = b2; iQl = iQl2; iQr = iQr2; Ktop = 128; g = blk - 2 * PB_INFO; }
        int c = t & 127;
        int sel = t >> 7;
        const float* W = sel ? Wr : Wl;
        float a = sel ? bias[c] : 0.0f;
        for (int d = 0; d < DI; ++d)
            a += info[g * DI + d] * W[(Ktop + d) * CO + c];
        (sel ? iQr : iQl)[g * CO + c] = a;
    }
}

// ================= CSR build =================
__global__ void k_hist(const int* __restrict__ dst, int* __restrict__ cnt) {
    int e = blockIdx.x * blockDim.x + threadIdx.x;
    if (e < NE) atomicAdd(&cnt[dst[e]], 1);
}

__global__ __launch_bounds__(256) void k_bsum(const int* __restrict__ cnt, int* __restrict__ bsum) {
    __shared__ int s[256];
    int i = blockIdx.x * 256 + threadIdx.x;
    s[threadIdx.x] = (i < NN) ? cnt[i] : 0;
    __syncthreads();
    for (int off = 128; off > 0; off >>= 1) {
        if (threadIdx.x < off) s[threadIdx.x] += s[threadIdx.x + off];
        __syncthreads();
    }
    if (threadIdx.x == 0) bsum[blockIdx.x] = s[0];
}

__global__ __launch_bounds__(256) void k_scanb(const int* __restrict__ bsum, int* __restrict__ bpre) {
    __shared__ int s[256];
    int tid = threadIdx.x;
    int v = (tid < NBLK) ? bsum[tid] : 0;
    s[tid] = v;
    __syncthreads();
    for (int off = 1; off < 256; off <<= 1) {
        int t = (tid >= off) ? s[tid - off] : 0;
        __syncthreads();
        s[tid] += t;
        __syncthreads();
    }
    if (tid < NBLK) bpre[tid] = s[tid] - v;
}

__global__ __launch_bounds__(256) void k_rowptr(const int* __restrict__ cnt, const int* __restrict__ bpre,
                                                int* __restrict__ rowptr, int* __restrict__ fillc) {
    __shared__ int s[256];
    int tid = threadIdx.x;
    int i = blockIdx.x * 256 + tid;
    int v = (i < NN) ? cnt[i] : 0;
    s[tid] = v;
    __syncthreads();
    for (int off = 1; off < 256; off <<= 1) {
        int t = (tid >= off) ? s[tid - off] : 0;
        __syncthreads();
        s[tid] += t;
        __syncthreads();
    }
    int pre = bpre[blockIdx.x] + s[tid] - v;
    if (i < NN) { rowptr[i] = pre; fillc[i] = 0; }
    if (i == NN - 1) rowptr[NN] = pre + v;
}

// csr entries are u16 (src < 65536) — halves scatter-write allocate traffic
__global__ void k_fill(const int* __restrict__ src, const int* __restrict__ dst,
                       const int* __restrict__ rowptr, int* __restrict__ fillc,
                       u16* __restrict__ csr) {
    int e = blockIdx.x * blockDim.x + threadIdx.x;
    if (e >= NE) return;
    int d = dst[e];
    int p = atomicAdd(&fillc[d], 1);
    csr[rowptr[d] + p] = (u16)src[e];
}

// ================= MFMA GEMM + fused combine =================
template<int K>
__global__ __launch_bounds__(256) void k_mfma(const u16* __restrict__ A,
                                              const u16* __restrict__ WTg,
                                              const int* __restrict__ batch,
                                              const float* __restrict__ iQl,
                                              const float* __restrict__ iQr,
                                              u16* __restrict__ zlp,
                                              u16* __restrict__ zq) {
    constexpr int PITCH = K + 8;
    __shared__ short lds[256 * PITCH];

    int tid  = threadIdx.x;
    int w    = tid >> 6;
    int lane = tid & 63;
    int quad = lane >> 4;
    int l15  = lane & 15;

    constexpr int CH = 256 * K / 8;
    const uint4* wp = (const uint4*)WTg;
    for (int c = tid; c < CH; c += 256) {
        int n  = c / (K / 8);
        int ko = (c - n * (K / 8)) * 8;
        *(uint4*)&lds[n * PITCH + ko] = wp[c];
    }
    __syncthreads();

    int i0 = blockIdx.x * 128 + w * 32;
    int r0 = i0 + l15;       if (r0 >= NN) r0 = NN - 1;
    int r1 = i0 + 16 + l15;  if (r1 >= NN) r1 = NN - 1;
    const short* A0 = (const short*)A + (size_t)r0 * K;
    const short* A1 = (const short*)A + (size_t)r1 * K;

    f32x4 acc[2][16];
#pragma unroll
    for (int rt = 0; rt < 2; ++rt)
#pragma unroll
        for (int ct = 0; ct < 16; ++ct)
            acc[rt][ct] = (f32x4){0.f, 0.f, 0.f, 0.f};

#pragma unroll
    for (int ks = 0; ks < K / 32; ++ks) {
        int ka = ks * 32 + quad * 8;
        bf16x8 a0 = *(const bf16x8*)(A0 + ka);
        bf16x8 a1 = *(const bf16x8*)(A1 + ka);
#pragma unroll
        for (int ct = 0; ct < 16; ++ct) {
            bf16x8 b = *(const bf16x8*)&lds[(ct * 16 + l15) * PITCH + ka];
            acc[0][ct] = __builtin_amdgcn_mfma_f32_16x16x32_bf16(a0, b, acc[0][ct], 0, 0, 0);
            acc[1][ct] = __builtin_amdgcn_mfma_f32_16x16x32_bf16(a1, b, acc[1][ct], 0, 0, 0);
        }
    }

#pragma unroll
    for (int rt = 0; rt < 2; ++rt) {
#pragma unroll
        for (int reg = 0; reg < 4; ++reg) {
            int row = i0 + rt * 16 + quad * 4 + reg;
            if (row < NN) {
                int b = batch[row];
                const float* ql = &iQl[b * CO];
                const float* qr = &iQr[b * CO];
                u16* lp = zlp + (size_t)row * CO;
                u16* qp = zq  + (size_t)row * CO;
#pragma unroll
                for (int ct = 0; ct < 8; ++ct) {
                    int col = ct * 16 + l15;
                    lp[col] = f2b(acc[rt][ct][reg] + ql[col]);
                }
#pragma unroll
                for (int ct = 8; ct < 16; ++ct) {
                    int col = ct * 16 + l15 - 128;
                    qp[col] = f2b(acc[rt][ct][reg] + qr[col]);
                }
            }
        }
    }
}

// ================= gather-mean: h = mean(zlp[nbrs]) + zq =================
__global__ __launch_bounds__(256) void k_gatherb(const u32* __restrict__ zlp, const u32* __restrict__ zq,
                                                 const int* __restrict__ rowptr, const u16* __restrict__ csr,
                                                 u32* __restrict__ hout) {
    int wave = threadIdx.x >> 6;
    int lane = threadIdx.x & 63;
    int i = blockIdx.x * 4 + wave;
    if (i >= NN) return;
    int s0 = rowptr[i], s1 = rowptr[i + 1];
    float a0 = 0.f, a1 = 0.f, b0 = 0.f, b1 = 0.f;
    float c0 = 0.f, c1 = 0.f, d0 = 0.f, d1 = 0.f;
    int e = s0;
    for (; e + 7 < s1; e += 8) {
        int sA = csr[e],     sB = csr[e + 1], sC = csr[e + 2], sD = csr[e + 3];
        int sE = csr[e + 4], sF = csr[e + 5], sG = csr[e + 6], sH = csr[e + 7];
        u32 uA = zlp[sA * 64 + lane];
        u32 uB = zlp[sB * 64 + lane];
        u32 uC = zlp[sC * 64 + lane];
        u32 uD = zlp[sD * 64 + lane];
        u32 uE = zlp[sE * 64 + lane];
        u32 uF = zlp[sF * 64 + lane];
        u32 uG = zlp[sG * 64 + lane];
        u32 uH = zlp[sH * 64 + lane];
        a0 += blo(uA) + blo(uB); a1 += bhi(uA) + bhi(uB);
        b0 += blo(uC) + blo(uD); b1 += bhi(uC) + bhi(uD);
        c0 += blo(uE) + blo(uF); c1 += bhi(uE) + bhi(uF);
        d0 += blo(uG) + blo(uH); d1 += bhi(uG) + bhi(uH);
    }
    for (; e + 1 < s1; e += 2) {
        int sA = csr[e], sB = csr[e + 1];
        u32 uA = zlp[sA * 64 + lane];
        u32 uB = zlp[sB * 64 + lane];
        a0 += blo(uA) + blo(uB); a1 += bhi(uA) + bhi(uB);
    }
    if (e < s1) {
        u32 uA = zlp[csr[e] * 64 + lane];
        a0 += blo(uA); a1 += bhi(uA);
    }
    a0 += b0 + c0 + d0;
    a1 += b1 + c1 + d1;
    float r = 1.0f / fmaxf((float)(s1 - s0), 1.0f);
    u32 q = zq[i * 64 + lane];
    float h0 = a0 * r + blo(q);
    float h1 = a1 * r + bhi(q);
    hout[i * 64 + lane] = (u32)f2b(h0) | ((u32)f2b(h1) << 16);
}

// ================= fused pool + FC head =================
__global__ __launch_bounds__(384) void k_poolfc(const u16* __restrict__ h1, const u16* __restrict__ h2,
                                                const u16* __restrict__ h3, const int* __restrict__ start,
                                                const float* __restrict__ W1, const float* __restrict__ b1,
                                                const float* __restrict__ W2, const float* __restrict__ b2,
                                                float* __restrict__ out) {
    __shared__ float s_g[F1I];
    __shared__ float s_z[F1O];
    int gr = blockIdx.x;
    int c  = threadIdx.x;
    int sel = c >> 7;
    int cc  = c & 127;
    const u16* hb = (sel == 0) ? h1 : (sel == 1) ? h2 : h3;
    int s = start[gr], e = start[gr + 1];
    float m0 = -FLT_MAX, m1 = -FLT_MAX;
    int n = s;
    for (; n + 1 < e; n += 2) {
        m0 = fmaxf(m0, b2f(hb[n * 128 + cc]));
        m1 = fmaxf(m1, b2f(hb[(n + 1) * 128 + cc]));
    }
    if (n < e) m0 = fmaxf(m0, b2f(hb[n * 128 + cc]));
    s_g[c] = fmaxf(m0, m1);
    __syncthreads();
    if (c < F1O) {
        float acc = b1[c];
        for (int k = 0; k < F1I; ++k) acc += s_g[k] * W1[k * F1O + c];
        s_z[c] = fmaxf(acc, 0.0f);
    }
    __syncthreads();
    if (c < F2O) {
        float a = b2[c];
        for (int k = 0; k < F1O; ++k) a += s_z[k] * W2[k * F2O + c];
        out[gr * F2O + c] = a;
    }
}

extern "C" void kernel_launch(void* const* d_in, const int* in_sizes, int n_in,
                              void* d_out, int out_size, void* d_ws, size_t ws_size,
                              hipStream_t stream) {
    const float* x     = (const float*)d_in[0];
    const int*   eidx  = (const int*)d_in[1];
    const int*   batch = (const int*)d_in[2];
    const float* info  = (const float*)d_in[3];
    const float* Wl0 = (const float*)d_in[4];
    const float* Wr0 = (const float*)d_in[5];
    const float* b0  = (const float*)d_in[6];
    const float* Wl1 = (const float*)d_in[7];
    const float* Wr1 = (const float*)d_in[8];
    const float* b1  = (const float*)d_in[9];
    const float* Wl2 = (const float*)d_in[10];
    const float* Wr2 = (const float*)d_in[11];
    const float* b2  = (const float*)d_in[12];
    const float* Wfc1  = (const float*)d_in[13];
    const float* bfc1  = (const float*)d_in[14];
    const float* Wfc2  = (const float*)d_in[15];
    const float* bfc2  = (const float*)d_in[16];
    float* out = (float*)d_out;

    const int* src = eidx;
    const int* dst = eidx + NE;

    // workspace layout (byte offsets, 16B-aligned)
    char* W = (char*)d_ws;
    u16* xb     = (u16*)(W + 0);             // 50000*96 bf16
    u16* h1     = (u16*)(W + 9600000);       // 50000*128 bf16 each
    u16* h2     = (u16*)(W + 22400000);
    u16* h3     = (u16*)(W + 35200000);
    u16* zlp    = (u16*)(W + 48000000);      // 50000*128 bf16
    u16* zq     = (u16*)(W + 60800000);
    u16* WT0    = (u16*)(W + 73600000);      // 256*96
    u16* WT1    = (u16*)(W + 73649152);      // 256*128
    u16* WT2    = (u16*)(W + 73714688);
    float* iQl0 = (float*)(W + 73780224);    // 500*128 f32 each
    float* iQr0 = (float*)(W + 74036224);
    float* iQl1 = (float*)(W + 74292224);
    float* iQr1 = (float*)(W + 74548224);
    float* iQl2 = (float*)(W + 74804224);
    float* iQr2 = (float*)(W + 75060224);
    int* start  = (int*)(W + 75316224);      // NG+1
    int* rowptr = (int*)(W + 75318272);      // NN+1
    int* cnt    = (int*)(W + 75518336);      // NN
    int* fillc  = (int*)(W + 75718336);      // NN
    u16* csr    = (u16*)(W + 75918336);      // NE u16
    int* bsum   = (int*)(W + 77518336);      // NBLK
    int* bpre   = (int*)(W + 77519360);      // NBLK

    // ---- fused prep (zero cnt | starts | cast | wt | infow) ----
    k_prep<<<PREP_GRID, 256, 0, stream>>>(x, batch, info,
        Wl0, Wr0, b0, Wl1, Wr1, b1, Wl2, Wr2, b2,
        cnt, start, xb, WT0, WT1, WT2, iQl0, iQr0, iQl1, iQr1, iQl2, iQr2);

    // ---- CSR chain ----
    k_hist<<<(NE + 255) / 256, 256, 0, stream>>>(dst, cnt);
    k_bsum<<<NBLK, 256, 0, stream>>>(cnt, bsum);
    k_scanb<<<1, 256, 0, stream>>>(bsum, bpre);
    k_rowptr<<<NBLK, 256, 0, stream>>>(cnt, bpre, rowptr, fillc);
    k_fill<<<(NE + 255) / 256, 256, 0, stream>>>(src, dst, rowptr, fillc, csr);

    const int gGemm = (NN + 127) / 128;
    const int gGath = (NN + 3) / 4;

    // ---- layer 0 ----
    k_mfma<96><<<gGemm, 256, 0, stream>>>(xb, WT0, batch, iQl0, iQr0, zlp, zq);
    k_gatherb<<<gGath, 256, 0, stream>>>((const u32*)zlp, (const u32*)zq, rowptr, csr, (u32*)h1);

    // ---- layer 1 ----
    k_mfma<128><<<gGemm, 256, 0, stream>>>(h1, WT1, batch, iQl1, iQr1, zlp, zq);
    k_gatherb<<<gGath, 256, 0, stream>>>((const u32*)zlp, (const u32*)zq, rowptr, csr, (u32*)h2);

    // ---- layer 2 ----
    k_mfma<128><<<gGemm, 256, 0, stream>>>(h2, WT2, batch, iQl2, iQr2, zlp, zq);
    k_gatherb<<<gGath, 256, 0, stream>>>((const u32*)zlp, (const u32*)zq, rowptr, csr, (u32*)h3);

    // ---- fused pool + head ----
    k_poolfc<<<NG, 384, 0, stream>>>(h1, h2, h3, start, Wfc1, bfc1, Wfc2, bfc2, out);
}

// Round 6
// 367.656 us; speedup vs baseline: 14.8167x; 1.0001x over previous
//
#include <hip/hip_runtime.h>
#include <hip/hip_bf16.h>
#include <float.h>

#define NN 50000
#define NE 800000
#define DF 96
#define DI 32
#define CO 128          // conv out per layer
#define NG 500
#define HC 384
#define F1I 384
#define F1O 160
#define F2O 10
#define NBLK 196        // ceil(NN/256)
#define DPX 6250        // dst nodes per XCD partition (NN/8)

typedef unsigned int  u32;
typedef unsigned short u16;
typedef short bf16x8 __attribute__((ext_vector_type(8)));
typedef float f32x4  __attribute__((ext_vector_type(4)));

__device__ __forceinline__ u16 f2b(float f) {
    __hip_bfloat16 h = __float2bfloat16(f);
    return *reinterpret_cast<u16*>(&h);
}
__device__ __forceinline__ float b2f(u16 u) {
    return __uint_as_float(((u32)u) << 16);
}
__device__ __forceinline__ float blo(u32 u) { return __uint_as_float(u << 16); }
__device__ __forceinline__ float bhi(u32 u) { return __uint_as_float(u & 0xffff0000u); }

// ================= fused prep: zero cnt | starts | cast x | wt x3 | infow x3 =================
#define PB_CNT    196
#define PB_STARTS 196
#define PB_CAST   4688   // NN*96/4 = 1,200,000 threads
#define PB_WT0    96     // 256*96
#define PB_WT1    128    // 256*128
#define PB_WT2    128
#define PB_INFO   500
#define PREP_GRID (PB_CNT + PB_STARTS + PB_CAST + PB_WT0 + PB_WT1 + PB_WT2 + 3 * PB_INFO)

__global__ __launch_bounds__(256) void k_prep(
        const float* __restrict__ x, const int* __restrict__ batch, const float* __restrict__ info,
        const float* __restrict__ Wl0, const float* __restrict__ Wr0, const float* __restrict__ b0,
        const float* __restrict__ Wl1, const float* __restrict__ Wr1, const float* __restrict__ b1,
        const float* __restrict__ Wl2, const float* __restrict__ Wr2, const float* __restrict__ b2,
        int* __restrict__ cnt, int* __restrict__ start, u16* __restrict__ xb,
        u16* __restrict__ WT0, u16* __restrict__ WT1, u16* __restrict__ WT2,
        float* __restrict__ iQl0, float* __restrict__ iQr0,
        float* __restrict__ iQl1, float* __restrict__ iQr1,
        float* __restrict__ iQl2, float* __restrict__ iQr2) {
    int blk = blockIdx.x;
    int t = threadIdx.x;
    if (blk < PB_CNT) {
        int i = blk * 256 + t;
        if (i < NN) cnt[i] = 0;
        return;
    }
    blk -= PB_CNT;
    if (blk < PB_STARTS) {
        int i = blk * 256 + t;
        if (i >= NN) return;
        int b = batch[i];
        if (i == 0) { for (int g = 0; g <= b; ++g) start[g] = 0; }
        else {
            int p = batch[i - 1];
            if (p != b) for (int g = p + 1; g <= b; ++g) start[g] = i;
        }
        if (i == NN - 1) { for (int g = b + 1; g <= NG; ++g) start[g] = NN; }
        return;
    }
    blk -= PB_STARTS;
    if (blk < PB_CAST) {
        int tid = blk * 256 + t;
        if (tid >= NN * DF / 4) return;
        float4 v = *(const float4*)&x[tid * 4];
        ushort4 o;
        o.x = f2b(v.x); o.y = f2b(v.y); o.z = f2b(v.z); o.w = f2b(v.w);
        *(ushort4*)&xb[tid * 4] = o;
        return;
    }
    blk -= PB_CAST;
    if (blk < PB_WT0 + PB_WT1 + PB_WT2) {
        const float* Wl; const float* Wr; u16* WT; int K; int rel;
        if (blk < PB_WT0) { Wl = Wl0; Wr = Wr0; WT = WT0; K = 96;  rel = blk; }
        else if (blk < PB_WT0 + PB_WT1) { Wl = Wl1; Wr = Wr1; WT = WT1; K = 128; rel = blk - PB_WT0; }
        else { Wl = Wl2; Wr = Wr2; WT = WT2; K = 128; rel = blk - PB_WT0 - PB_WT1; }
        int tid = rel * 256 + t;
        if (tid >= 256 * K) return;
        int n = tid / K;
        int k = tid - n * K;
        float v = (n < CO) ? Wl[k * CO + n] : Wr[k * CO + (n - CO)];
        WT[tid] = f2b(v);
        return;
    }
    blk -= PB_WT0 + PB_WT1 + PB_WT2;
    {
        const float* Wl; const float* Wr; const float* bias; float* iQl; float* iQr; int Ktop; int g;
        if (blk < PB_INFO) { Wl = Wl0; Wr = Wr0; bias = b0; iQl = iQl0; iQr = iQr0; Ktop = 96;  g = blk; }
        else if (blk < 2 * PB_INFO) { Wl = Wl1; Wr = Wr1; bias = b1; iQl = iQl1; iQr = iQr1; Ktop = 128; g = blk - PB_INFO; }
        else { Wl = Wl2; Wr = Wr2; bias = b2; iQl = iQl2; iQr = iQr2; Ktop = 128; g = blk - 2 * PB_INFO; }
        int c = t & 127;
        int sel = t >> 7;
        const float* W = sel ? Wr : Wl;
        float a = sel ? bias[c] : 0.0f;
        for (int d = 0; d < DI; ++d)
            a += info[g * DI + d] * W[(Ktop + d) * CO + c];
        (sel ? iQr : iQl)[g * CO + c] = a;
    }
}

// ================= CSR build =================
__global__ void k_hist(const int* __restrict__ dst, int* __restrict__ cnt) {
    int e = blockIdx.x * blockDim.x + threadIdx.x;
    if (e < NE) atomicAdd(&cnt[dst[e]], 1);
}

__global__ __launch_bounds__(256) void k_bsum(const int* __restrict__ cnt, int* __restrict__ bsum) {
    __shared__ int s[256];
    int i = blockIdx.x * 256 + threadIdx.x;
    s[threadIdx.x] = (i < NN) ? cnt[i] : 0;
    __syncthreads();
    for (int off = 128; off > 0; off >>= 1) {
        if (threadIdx.x < off) s[threadIdx.x] += s[threadIdx.x + off];
        __syncthreads();
    }
    if (threadIdx.x == 0) bsum[blockIdx.x] = s[0];
}

__global__ __launch_bounds__(256) void k_scanb(const int* __restrict__ bsum, int* __restrict__ bpre) {
    __shared__ int s[256];
    int tid = threadIdx.x;
    int v = (tid < NBLK) ? bsum[tid] : 0;
    s[tid] = v;
    __syncthreads();
    for (int off = 1; off < 256; off <<= 1) {
        int t = (tid >= off) ? s[tid - off] : 0;
        __syncthreads();
        s[tid] += t;
        __syncthreads();
    }
    if (tid < NBLK) bpre[tid] = s[tid] - v;
}

__global__ __launch_bounds__(256) void k_rowptr(const int* __restrict__ cnt, const int* __restrict__ bpre,
                                                int* __restrict__ rowptr, int* __restrict__ fillc) {
    __shared__ int s[256];
    int tid = threadIdx.x;
    int i = blockIdx.x * 256 + tid;
    int v = (i < NN) ? cnt[i] : 0;
    s[tid] = v;
    __syncthreads();
    for (int off = 1; off < 256; off <<= 1) {
        int t = (tid >= off) ? s[tid - off] : 0;
        __syncthreads();
        s[tid] += t;
        __syncthreads();
    }
    int pre = bpre[blockIdx.x] + s[tid] - v;
    if (i < NN) { rowptr[i] = pre; fillc[i] = 0; }
    if (i == NN - 1) rowptr[NN] = pre + v;
}

// XCD-partitioned bucket fill: block handles one 256-edge chunk for one dst range.
// blockIdx & 7 round-robins XCDs (dispatch heuristic) -> csr/fillc lines stay XCD-local.
__global__ __launch_bounds__(256) void k_fill(const int* __restrict__ src, const int* __restrict__ dst,
                                              const int* __restrict__ rowptr, int* __restrict__ fillc,
                                              u16* __restrict__ csr) {
    int xcd   = blockIdx.x & 7;
    int chunk = blockIdx.x >> 3;
    int lo = xcd * DPX;
    int hi = lo + DPX;
    int e = chunk * 256 + threadIdx.x;
    if (e >= NE) return;
    int d = dst[e];
    if (d >= lo && d < hi) {
        int p = atomicAdd(&fillc[d], 1);
        csr[rowptr[d] + p] = (u16)src[e];
    }
}

// ================= MFMA GEMM + fused combine =================
template<int K>
__global__ __launch_bounds__(256) void k_mfma(const u16* __restrict__ A,
                                              const u16* __restrict__ WTg,
                                              const int* __restrict__ batch,
                                              const float* __restrict__ iQl,
                                              const float* __restrict__ iQr,
                                              u16* __restrict__ zlp,
                                              u16* __restrict__ zq) {
    constexpr int PITCH = K + 8;
    __shared__ short lds[256 * PITCH];

    int tid  = threadIdx.x;
    int w    = tid >> 6;
    int lane = tid & 63;
    int quad = lane >> 4;
    int l15  = lane & 15;

    constexpr int CH = 256 * K / 8;
    const uint4* wp = (const uint4*)WTg;
    for (int c = tid; c < CH; c += 256) {
        int n  = c / (K / 8);
        int ko = (c - n * (K / 8)) * 8;
        *(uint4*)&lds[n * PITCH + ko] = wp[c];
    }
    __syncthreads();

    int i0 = blockIdx.x * 128 + w * 32;
    int r0 = i0 + l15;       if (r0 >= NN) r0 = NN - 1;
    int r1 = i0 + 16 + l15;  if (r1 >= NN) r1 = NN - 1;
    const short* A0 = (const short*)A + (size_t)r0 * K;
    const short* A1 = (const short*)A + (size_t)r1 * K;

    f32x4 acc[2][16];
#pragma unroll
    for (int rt = 0; rt < 2; ++rt)
#pragma unroll
        for (int ct = 0; ct < 16; ++ct)
            acc[rt][ct] = (f32x4){0.f, 0.f, 0.f, 0.f};

#pragma unroll
    for (int ks = 0; ks < K / 32; ++ks) {
        int ka = ks * 32 + quad * 8;
        bf16x8 a0 = *(const bf16x8*)(A0 + ka);
        bf16x8 a1 = *(const bf16x8*)(A1 + ka);
#pragma unroll
        for (int ct = 0; ct < 16; ++ct) {
            bf16x8 b = *(const bf16x8*)&lds[(ct * 16 + l15) * PITCH + ka];
            acc[0][ct] = __builtin_amdgcn_mfma_f32_16x16x32_bf16(a0, b, acc[0][ct], 0, 0, 0);
            acc[1][ct] = __builtin_amdgcn_mfma_f32_16x16x32_bf16(a1, b, acc[1][ct], 0, 0, 0);
        }
    }

#pragma unroll
    for (int rt = 0; rt < 2; ++rt) {
#pragma unroll
        for (int reg = 0; reg < 4; ++reg) {
            int row = i0 + rt * 16 + quad * 4 + reg;
            if (row < NN) {
                int b = batch[row];
                const float* ql = &iQl[b * CO];
                const float* qr = &iQr[b * CO];
                u16* lp = zlp + (size_t)row * CO;
                u16* qp = zq  + (size_t)row * CO;
#pragma unroll
                for (int ct = 0; ct < 8; ++ct) {
                    int col = ct * 16 + l15;
                    lp[col] = f2b(acc[rt][ct][reg] + ql[col]);
                }
#pragma unroll
                for (int ct = 8; ct < 16; ++ct) {
                    int col = ct * 16 + l15 - 128;
                    qp[col] = f2b(acc[rt][ct][reg] + qr[col]);
                }
            }
        }
    }
}

// ================= gather-mean: h = mean(zlp[nbrs]) + zq =================
// split-wave: half-wave (32 lanes) covers one 256B row via uint2 -> 2 rows per load instr;
// 4 chains (8 neighbors in flight); cross-half combine via shfl_xor(32).
__global__ __launch_bounds__(256) void k_gatherb(const u32* __restrict__ zlp, const u32* __restrict__ zq,
                                                 const int* __restrict__ rowptr, const u16* __restrict__ csr,
                                                 u32* __restrict__ hout) {
    int wave = threadIdx.x >> 6;
    int lane = threadIdx.x & 63;
    int half = lane >> 5;
    int l32  = lane & 31;
    int i = blockIdx.x * 4 + wave;
    if (i >= NN) return;
    int s0 = rowptr[i], s1 = rowptr[i + 1];
    int deg = s1 - s0;

    float a[4] = {0.f, 0.f, 0.f, 0.f};
    float b[4] = {0.f, 0.f, 0.f, 0.f};
    float c[4] = {0.f, 0.f, 0.f, 0.f};
    float d[4] = {0.f, 0.f, 0.f, 0.f};

    int e = s0;
    for (; e + 7 < s1; e += 8) {
        int n0 = csr[e + half];
        int n1 = csr[e + 2 + half];
        int n2 = csr[e + 4 + half];
        int n3 = csr[e + 6 + half];
        uint2 u0 = *(const uint2*)(zlp + n0 * 64 + l32 * 2);
        uint2 u1 = *(const uint2*)(zlp + n1 * 64 + l32 * 2);
        uint2 u2 = *(const uint2*)(zlp + n2 * 64 + l32 * 2);
        uint2 u3 = *(const uint2*)(zlp + n3 * 64 + l32 * 2);
        a[0] += blo(u0.x); a[1] += bhi(u0.x); a[2] += blo(u0.y); a[3] += bhi(u0.y);
        b[0] += blo(u1.x); b[1] += bhi(u1.x); b[2] += blo(u1.y); b[3] += bhi(u1.y);
        c[0] += blo(u2.x); c[1] += bhi(u2.x); c[2] += blo(u2.y); c[3] += bhi(u2.y);
        d[0] += blo(u3.x); d[1] += bhi(u3.x); d[2] += blo(u3.y); d[3] += bhi(u3.y);
    }
    for (; e + 1 < s1; e += 2) {
        int n0 = csr[e + half];
        uint2 u0 = *(const uint2*)(zlp + n0 * 64 + l32 * 2);
        a[0] += blo(u0.x); a[1] += bhi(u0.x); a[2] += blo(u0.y); a[3] += bhi(u0.y);
    }
    if (e < s1 && half == 0) {
        int n0 = csr[e];
        uint2 u0 = *(const uint2*)(zlp + n0 * 64 + l32 * 2);
        a[0] += blo(u0.x); a[1] += bhi(u0.x); a[2] += blo(u0.y); a[3] += bhi(u0.y);
    }
#pragma unroll
    for (int j = 0; j < 4; ++j) {
        a[j] += b[j] + c[j] + d[j];
        a[j] += __shfl_xor(a[j], 32);
    }
    if (half == 0) {
        float r = 1.0f / fmaxf((float)deg, 1.0f);
        uint2 q = *(const uint2*)(zq + i * 64 + l32 * 2);
        float h0 = a[0] * r + blo(q.x);
        float h1 = a[1] * r + bhi(q.x);
        float h2 = a[2] * r + blo(q.y);
        float h3 = a[3] * r + bhi(q.y);
        uint2 o;
        o.x = (u32)f2b(h0) | ((u32)f2b(h1) << 16);
        o.y = (u32)f2b(h2) | ((u32)f2b(h3) << 16);
        *(uint2*)(hout + i * 64 + l32 * 2) = o;
    }
}

// ================= fused pool + FC head =================
__global__ __launch_bounds__(384) void k_poolfc(const u16* __restrict__ h1, const u16* __restrict__ h2,
                                                const u16* __restrict__ h3, const int* __restrict__ start,
                                                const float* __restrict__ W1, const float* __restrict__ b1,
                                                const float* __restrict__ W2, const float* __restrict__ b2,
                                                float* __restrict__ out) {
    __shared__ float s_g[F1I];
    __shared__ float s_z[F1O];
    int gr = blockIdx.x;
    int c  = threadIdx.x;
    int sel = c >> 7;
    int cc  = c & 127;
    const u16* hb = (sel == 0) ? h1 : (sel == 1) ? h2 : h3;
    int s = start[gr], e = start[gr + 1];
    float m0 = -FLT_MAX, m1 = -FLT_MAX;
    int n = s;
    for (; n + 1 < e; n += 2) {
        m0 = fmaxf(m0, b2f(hb[n * 128 + cc]));
        m1 = fmaxf(m1, b2f(hb[(n + 1) * 128 + cc]));
    }
    if (n < e) m0 = fmaxf(m0, b2f(hb[n * 128 + cc]));
    s_g[c] = fmaxf(m0, m1);
    __syncthreads();
    if (c < F1O) {
        float acc = b1[c];
        for (int k = 0; k < F1I; ++k) acc += s_g[k] * W1[k * F1O + c];
        s_z[c] = fmaxf(acc, 0.0f);
    }
    __syncthreads();
    if (c < F2O) {
        float a = b2[c];
        for (int k = 0; k < F1O; ++k) a += s_z[k] * W2[k * F2O + c];
        out[gr * F2O + c] = a;
    }
}

extern "C" void kernel_launch(void* const* d_in, const int* in_sizes, int n_in,
                              void* d_out, int out_size, void* d_ws, size_t ws_size,
                              hipStream_t stream) {
    const float* x     = (const float*)d_in[0];
    const int*   eidx  = (const int*)d_in[1];
    const int*   batch = (const int*)d_in[2];
    const float* info  = (const float*)d_in[3];
    const float* Wl0 = (const float*)d_in[4];
    const float* Wr0 = (const float*)d_in[5];
    const float* b0  = (const float*)d_in[6];
    const float* Wl1 = (const float*)d_in[7];
    const float* Wr1 = (const float*)d_in[8];
    const float* b1  = (const float*)d_in[9];
    const float* Wl2 = (const float*)d_in[10];
    const float* Wr2 = (const float*)d_in[11];
    const float* b2  = (const float*)d_in[12];
    const float* Wfc1  = (const float*)d_in[13];
    const float* bfc1  = (const float*)d_in[14];
    const float* Wfc2  = (const float*)d_in[15];
    const float* bfc2  = (const float*)d_in[16];
    float* out = (float*)d_out;

    const int* src = eidx;
    const int* dst = eidx + NE;

    // workspace layout (byte offsets, 16B-aligned)
    char* W = (char*)d_ws;
    u16* xb     = (u16*)(W + 0);             // 50000*96 bf16
    u16* h1     = (u16*)(W + 9600000);       // 50000*128 bf16 each
    u16* h2     = (u16*)(W + 22400000);
    u16* h3     = (u16*)(W + 35200000);
    u16* zlp    = (u16*)(W + 48000000);      // 50000*128 bf16
    u16* zq     = (u16*)(W + 60800000);
    u16* WT0    = (u16*)(W + 73600000);      // 256*96
    u16* WT1    = (u16*)(W + 73649152);      // 256*128
    u16* WT2    = (u16*)(W + 73714688);
    float* iQl0 = (float*)(W + 73780224);    // 500*128 f32 each
    float* iQr0 = (float*)(W + 74036224);
    float* iQl1 = (float*)(W + 74292224);
    float* iQr1 = (float*)(W + 74548224);
    float* iQl2 = (float*)(W + 74804224);
    float* iQr2 = (float*)(W + 75060224);
    int* start  = (int*)(W + 75316224);      // NG+1
    int* rowptr = (int*)(W + 75318272);      // NN+1
    int* cnt    = (int*)(W + 75518336);      // NN
    int* fillc  = (int*)(W + 75718336);      // NN
    u16* csr    = (u16*)(W + 75918336);      // NE u16
    int* bsum   = (int*)(W + 77518336);      // NBLK
    int* bpre   = (int*)(W + 77519360);      // NBLK

    // ---- fused prep (zero cnt | starts | cast | wt | infow) ----
    k_prep<<<PREP_GRID, 256, 0, stream>>>(x, batch, info,
        Wl0, Wr0, b0, Wl1, Wr1, b1, Wl2, Wr2, b2,
        cnt, start, xb, WT0, WT1, WT2, iQl0, iQr0, iQl1, iQr1, iQl2, iQr2);

    // ---- CSR chain ----
    k_hist<<<(NE + 255) / 256, 256, 0, stream>>>(dst, cnt);
    k_bsum<<<NBLK, 256, 0, stream>>>(cnt, bsum);
    k_scanb<<<1, 256, 0, stream>>>(bsum, bpre);
    k_rowptr<<<NBLK, 256, 0, stream>>>(cnt, bpre, rowptr, fillc);
    k_fill<<<((NE + 255) / 256) * 8, 256, 0, stream>>>(src, dst, rowptr, fillc, csr);

    const int gGemm = (NN + 127) / 128;
    const int gGath = (NN + 3) / 4;

    // ---- layer 0 ----
    k_mfma<96><<<gGemm, 256, 0, stream>>>(xb, WT0, batch, iQl0, iQr0, zlp, zq);
    k_gatherb<<<gGath, 256, 0, stream>>>((const u32*)zlp, (const u32*)zq, rowptr, csr, (u32*)h1);

    // ---- layer 1 ----
    k_mfma<128><<<gGemm, 256, 0, stream>>>(h1, WT1, batch, iQl1, iQr1, zlp, zq);
    k_gatherb<<<gGath, 256, 0, stream>>>((const u32*)zlp, (const u32*)zq, rowptr, csr, (u32*)h2);

    // ---- layer 2 ----
    k_mfma<128><<<gGemm, 256, 0, stream>>>(h2, WT2, batch, iQl2, iQr2, zlp, zq);
    k_gatherb<<<gGath, 256, 0, stream>>>((const u32*)zlp, (const u32*)zq, rowptr, csr, (u32*)h3);

    // ---- fused pool + head ----
    k_poolfc<<<NG, 384, 0, stream>>>(h1, h2, h3, start, Wfc1, bfc1, Wfc2, bfc2, out);
}